// Round 1
// baseline (327.574 us; speedup 1.0000x reference)
//
#include <hip/hip_runtime.h>
#include <cmath>

#define H96 96
#define W96 96
#define HW  9216          // 96*96
#define NC  256
#define NB  2
#define NHEADS 8
#define HD  32
#define SCALE 0.17677669529663687f   // 1/sqrt(32)

// ---------------------------------------------------------------------------
// GEMM over feature maps: Cfm[b][m][hw] = sum_c A[m][c] * Bfm[b][c][hw]
// optional epilogue: + bias[m] + res[b][m][hw]
// A: [M][256] row-major. Grid: (18432/64, M/64), 256 threads, 4x4 microtile.
// ---------------------------------------------------------------------------
template<int EPI>
__global__ __launch_bounds__(256)
void gemm_fm(const float* __restrict__ A, const float* __restrict__ Bfm,
             float* __restrict__ Cfm, const float* __restrict__ bias,
             const float* __restrict__ res, int M)
{
    __shared__ float As[16][64];
    __shared__ float Bs[16][68];   // +4 pad

    const int t   = threadIdx.x;
    const int n0  = blockIdx.x * 64;
    const int m0  = blockIdx.y * 64;
    const int b   = n0 / HW;          // blocks never straddle batch (9216 % 64 == 0)
    const int hw0 = n0 - b * HW;
    const float* Bp = Bfm + (size_t)b * NC * HW + hw0;

    const int ty = t >> 4, tx = t & 15;
    const int arow = t >> 2, ac4 = (t & 3) * 4;   // A-tile load: 64 rows x 16 k
    const int bk = t >> 4,  bn4 = (t & 15) * 4;   // B-tile load: 16 k x 64 n

    float acc[4][4] = {};

    for (int k0 = 0; k0 < NC; k0 += 16) {
        const float4 av = *(const float4*)(A + (size_t)(m0 + arow) * NC + k0 + ac4);
        const float4 bv = *(const float4*)(Bp + (size_t)(k0 + bk) * HW + bn4);
        As[ac4 + 0][arow] = av.x;
        As[ac4 + 1][arow] = av.y;
        As[ac4 + 2][arow] = av.z;
        As[ac4 + 3][arow] = av.w;
        *(float4*)&Bs[bk][bn4] = bv;
        __syncthreads();
        #pragma unroll
        for (int kk = 0; kk < 16; ++kk) {
            const float4 a  = *(const float4*)&As[kk][ty * 4];
            const float4 bb = *(const float4*)&Bs[kk][tx * 4];
            const float a_[4] = {a.x, a.y, a.z, a.w};
            const float b_[4] = {bb.x, bb.y, bb.z, bb.w};
            #pragma unroll
            for (int i2 = 0; i2 < 4; ++i2)
                #pragma unroll
                for (int j2 = 0; j2 < 4; ++j2)
                    acc[i2][j2] = fmaf(a_[i2], b_[j2], acc[i2][j2]);
        }
        __syncthreads();
    }

    float* Cp = Cfm + (size_t)b * M * HW + hw0 + tx * 4;
    #pragma unroll
    for (int i2 = 0; i2 < 4; ++i2) {
        const int m = m0 + ty * 4 + i2;
        float4 v;
        v.x = acc[i2][0]; v.y = acc[i2][1]; v.z = acc[i2][2]; v.w = acc[i2][3];
        if constexpr (EPI) {
            const float bb = bias[m];
            const float4 rv = *(const float4*)(res + ((size_t)b * NC + m) * HW + hw0 + tx * 4);
            v.x += bb + rv.x; v.y += bb + rv.y; v.z += bb + rv.z; v.w += bb + rv.w;
        }
        *(float4*)(Cp + (size_t)m * HW) = v;
    }
}

// ---------------------------------------------------------------------------
// vsum[b][c][hw] = 3x3 zero-padded box sum of v map (qkv channels 512..767)
// ---------------------------------------------------------------------------
__global__ __launch_bounds__(256)
void boxsum_kernel(const float* __restrict__ qkv, float* __restrict__ vout)
{
    const int idx = blockIdx.x * 256 + threadIdx.x;  // < NB*NC*HW exactly
    const int hw = idx % HW;
    const int bc = idx / HW;
    const int b = bc / NC, c = bc - b * NC;
    const int ii = hw / W96, jj = hw - ii * W96;
    const float* p = qkv + ((size_t)b * 768 + 512 + c) * HW;
    float s = 0.f;
    #pragma unroll
    for (int dy = -1; dy <= 1; ++dy) {
        const int y = ii + dy;
        if (y < 0 || y >= H96) continue;
        #pragma unroll
        for (int dx = -1; dx <= 1; ++dx) {
            const int xc = jj + dx;
            if (xc < 0 || xc >= W96) continue;
            s += p[(size_t)y * W96 + xc];
        }
    }
    vout[(size_t)bc * HW + hw] = s;
}

// ---------------------------------------------------------------------------
// Attention: block = (16-pixel row strip, one head, one batch). 256 threads.
// Thread t: pixel px = t&15, softmax rows n = 2*(t>>4), 2*(t>>4)+1 (fully local).
// dots[n][m] = sum_s q_s[n]*k_s[m] over 3x3 window, zero-padded.
// out[n] = sum_m softmax(dots)[n][m] * vsum[m]
// ---------------------------------------------------------------------------
__global__ __launch_bounds__(256)
void attn_kernel(const float* __restrict__ qkv, const float* __restrict__ vsum,
                 float* __restrict__ att)
{
    __shared__ float qs[HD][56];     // [n][dy*18+dx], 54 used, pad to 56
    __shared__ float kst[54][36];    // [dy*18+dx][m], pad 32->36 (bank spread, 16B-aligned rows)
    __shared__ float vs[16][36];     // [px][m]

    const int t = threadIdx.x;
    const int strip = blockIdx.x;    // 0..575
    const int h = blockIdx.y;
    const int b = blockIdx.z;
    const int i0 = strip / 6;
    const int j0 = (strip - (strip / 6) * 6) * 16;

    const size_t qbase = ((size_t)b * 768 + h * HD) * HW;
    const size_t kbase = ((size_t)b * 768 + NC + h * HD) * HW;

    // stage q (row-layout) and k (transposed, channel-contiguous) neighborhoods
    for (int e = t; e < HD * 54; e += 256) {
        const int n = e / 54, r = e - n * 54;
        const int dy = r / 18, dx = r - dy * 18;
        const int gi = i0 - 1 + dy, gj = j0 - 1 + dx;
        float qv = 0.f, kv = 0.f;
        if (gi >= 0 && gi < H96 && gj >= 0 && gj < W96) {
            const size_t off = (size_t)gi * W96 + gj;
            qv = qkv[qbase + (size_t)n * HW + off];
            kv = qkv[kbase + (size_t)n * HW + off];
        }
        qs[n][r] = qv;
        kst[r][n] = kv;
    }
    // stage vsum for the 16 center pixels
    for (int e = t; e < 16 * HD; e += 256) {
        const int m = e >> 4, px = e & 15;
        vs[px][m] = vsum[((size_t)b * NC + h * HD + m) * HW + (size_t)i0 * W96 + j0 + px];
    }
    __syncthreads();

    const int px = t & 15;
    const int n0r = (t >> 4) * 2;

    float q0[9], q1[9];
    #pragma unroll
    for (int r9 = 0; r9 < 9; ++r9) {
        const int dy = r9 / 3, dj = r9 - dy * 3;
        const int si = dy * 18 + px + dj;
        q0[r9] = qs[n0r][si] * SCALE;
        q1[r9] = qs[n0r + 1][si] * SCALE;
    }

    float d0[32], d1[32];
    #pragma unroll
    for (int m = 0; m < 32; ++m) { d0[m] = 0.f; d1[m] = 0.f; }

    #pragma unroll
    for (int r9 = 0; r9 < 9; ++r9) {
        const int dy = r9 / 3, dj = r9 - dy * 3;
        const int si = dy * 18 + px + dj;
        const float4* kp = (const float4*)&kst[si][0];
        #pragma unroll
        for (int mb = 0; mb < 8; ++mb) {
            const float4 kv = kp[mb];
            d0[mb * 4 + 0] = fmaf(q0[r9], kv.x, d0[mb * 4 + 0]);
            d0[mb * 4 + 1] = fmaf(q0[r9], kv.y, d0[mb * 4 + 1]);
            d0[mb * 4 + 2] = fmaf(q0[r9], kv.z, d0[mb * 4 + 2]);
            d0[mb * 4 + 3] = fmaf(q0[r9], kv.w, d0[mb * 4 + 3]);
            d1[mb * 4 + 0] = fmaf(q1[r9], kv.x, d1[mb * 4 + 0]);
            d1[mb * 4 + 1] = fmaf(q1[r9], kv.y, d1[mb * 4 + 1]);
            d1[mb * 4 + 2] = fmaf(q1[r9], kv.z, d1[mb * 4 + 2]);
            d1[mb * 4 + 3] = fmaf(q1[r9], kv.w, d1[mb * 4 + 3]);
        }
    }

    // local softmax over m (each thread owns whole rows)
    float mx0 = d0[0], mx1 = d1[0];
    #pragma unroll
    for (int m = 1; m < 32; ++m) { mx0 = fmaxf(mx0, d0[m]); mx1 = fmaxf(mx1, d1[m]); }
    float s0 = 0.f, s1 = 0.f;
    #pragma unroll
    for (int m = 0; m < 32; ++m) {
        d0[m] = __expf(d0[m] - mx0); s0 += d0[m];
        d1[m] = __expf(d1[m] - mx1); s1 += d1[m];
    }

    float o0 = 0.f, o1 = 0.f;
    const float4* vp = (const float4*)&vs[px][0];
    #pragma unroll
    for (int mb = 0; mb < 8; ++mb) {
        const float4 vv = vp[mb];
        o0 += d0[mb * 4 + 0] * vv.x + d0[mb * 4 + 1] * vv.y + d0[mb * 4 + 2] * vv.z + d0[mb * 4 + 3] * vv.w;
        o1 += d1[mb * 4 + 0] * vv.x + d1[mb * 4 + 1] * vv.y + d1[mb * 4 + 2] * vv.z + d1[mb * 4 + 3] * vv.w;
    }
    o0 /= s0;
    o1 /= s1;

    const size_t obase = ((size_t)b * NC + h * HD + n0r) * HW + (size_t)i0 * W96 + j0 + px;
    att[obase] = o0;
    att[obase + HW] = o1;
}

// ---------------------------------------------------------------------------
extern "C" void kernel_launch(void* const* d_in, const int* in_sizes, int n_in,
                              void* d_out, int out_size, void* d_ws, size_t ws_size,
                              hipStream_t stream)
{
    (void)in_sizes; (void)n_in; (void)out_size; (void)ws_size;
    const float* x     = (const float*)d_in[0];
    const float* w_qkv = (const float*)d_in[1];
    const float* w_out = (const float*)d_in[2];
    const float* b_out = (const float*)d_in[3];
    float* out = (float*)d_out;

    float* qkv  = (float*)d_ws;                       // [B][768][HW]  56.6 MB
    float* vsum = qkv  + (size_t)NB * 768 * HW;       // [B][256][HW]  18.9 MB
    float* att  = vsum + (size_t)NB * NC * HW;        // [B][256][HW]  18.9 MB

    // 1) qkv = w_qkv @ x  (per-pixel 1x1 conv)
    gemm_fm<0><<<dim3(288, 12), 256, 0, stream>>>(w_qkv, x, qkv, nullptr, nullptr, 768);
    // 2) vsum = 3x3 box sum of v map (replaces unfold+PV-sum over s)
    boxsum_kernel<<<dim3(NB * NC * HW / 256), 256, 0, stream>>>(qkv, vsum);
    // 3) local attention per (strip, head, batch)
    attn_kernel<<<dim3(576, NHEADS, NB), 256, 0, stream>>>(qkv, vsum, att);
    // 4) out = w_out @ att + b_out + x
    gemm_fm<1><<<dim3(288, 4), 256, 0, stream>>>(w_out, att, out, b_out, x, 256);
}

// Round 2
// 219.062 us; speedup vs baseline: 1.4954x; 1.4954x over previous
//
#include <hip/hip_runtime.h>

#define H96 96
#define W96 96
#define HW  9216          // 96*96
#define NC  256
#define NB  2
#define NHEADS 8
#define HD  32
#define SCALE 0.17677669529663687f   // 1/sqrt(32)

typedef __attribute__((ext_vector_type(8))) short short8v;   // 8 bf16 (4 VGPRs)
typedef __attribute__((ext_vector_type(4))) float f32x4;

__device__ __forceinline__ ushort f2bf(float f) {
    unsigned u = __float_as_uint(f);
    u += 0x7FFFu + ((u >> 16) & 1u);          // round-to-nearest-even
    return (ushort)(u >> 16);
}
__device__ __forceinline__ float bf2f(ushort h) {
    return __uint_as_float(((unsigned)h) << 16);
}

// ---------------------------------------------------------------------------
// x [B][C][HW] fp32 -> xt [B][HW][C] bf16 (pixel-major, K-contiguous)
// ---------------------------------------------------------------------------
__global__ __launch_bounds__(256)
void x_to_bf16t(const float* __restrict__ x, ushort* __restrict__ xt)
{
    __shared__ float tile[32][33];
    const int t = threadIdx.x;
    const int hw0 = blockIdx.x * 32, c0 = blockIdx.y * 32, b = blockIdx.z;

    const int r = t >> 3, cc = (t & 7) * 4;
    const float4 v = *(const float4*)(x + ((size_t)b * NC + c0 + r) * HW + hw0 + cc);
    tile[r][cc + 0] = v.x; tile[r][cc + 1] = v.y; tile[r][cc + 2] = v.z; tile[r][cc + 3] = v.w;
    __syncthreads();

    const int hwr = t >> 3, c4 = (t & 7) * 4;
    ushort4 o;
    o.x = f2bf(tile[c4 + 0][hwr]);
    o.y = f2bf(tile[c4 + 1][hwr]);
    o.z = f2bf(tile[c4 + 2][hwr]);
    o.w = f2bf(tile[c4 + 3][hwr]);
    *(ushort4*)(xt + ((size_t)b * HW + hw0 + hwr) * NC + c0 + c4) = o;
}

// ---------------------------------------------------------------------------
// fp32 -> bf16 elementwise (weights). n must be multiple of 1024.
// ---------------------------------------------------------------------------
__global__ __launch_bounds__(256)
void conv_bf16(const float* __restrict__ w, ushort* __restrict__ o)
{
    const int i = (blockIdx.x * 256 + threadIdx.x) * 4;
    const float4 v = *(const float4*)(w + i);
    ushort4 u;
    u.x = f2bf(v.x); u.y = f2bf(v.y); u.z = f2bf(v.z); u.w = f2bf(v.w);
    *(ushort4*)(o + i) = u;
}

// ---------------------------------------------------------------------------
// MFMA GEMM: C[b][m][hw] = sum_c A[m][c] * Bt[(b*HW+hw)][c]
// A: [M][256] bf16 row-major (K contiguous). Bt: [18432][256] bf16.
// 128x128 tile, BK=64, 4 waves (2x2), each wave 64x64 (4x4 frags 16x16).
// global_load_lds w=16, LDS [row][64] bf16 with chunk XOR-swizzle (row&7),
// swizzle applied to BOTH the global source addr and the ds_read addr.
// EPI=0: write bf16 [b][Mtot][HW]. EPI=1: fp32 + bias + res, write [b][256][HW].
// ---------------------------------------------------------------------------
__device__ __forceinline__ void stage_tile(const ushort* __restrict__ g, ushort* lds,
                                           int w, int lane)
{
    const int lr  = lane >> 3;                  // row within 8-row chunk
    const int swz = ((lane & 7) ^ lr) * 8;      // pre-swizzled k-chunk (ushort units)
    #pragma unroll
    for (int ii = 0; ii < 4; ++ii) {
        const int rowbase = w * 32 + ii * 8;
        const ushort* src = g + (size_t)(rowbase + lr) * NC + swz;
        __builtin_amdgcn_global_load_lds((const __attribute__((address_space(1))) void*)src,
                                         (__attribute__((address_space(3))) void*)(lds + rowbase * 64),
                                         16, 0, 0);
    }
}

template<int EPI>
__global__ __launch_bounds__(256)
void gemm_mfma(const ushort* __restrict__ A, const ushort* __restrict__ Bt,
               void* __restrict__ Cout, const float* __restrict__ bias,
               const float* __restrict__ res, int Mtot)
{
    __shared__ __align__(16) ushort As[128 * 64];
    __shared__ __align__(16) ushort Bs[128 * 64];

    const int t = threadIdx.x;
    const int lane = t & 63, w = t >> 6;
    const int wm = w >> 1, wn = w & 1;
    const int n0 = blockIdx.x * 128;            // global pixel (across B*HW)
    const int m0 = blockIdx.y * 128;

    const ushort* Ag = A + (size_t)m0 * NC;
    const ushort* Bg = Bt + (size_t)n0 * NC;

    f32x4 acc[4][4];
    #pragma unroll
    for (int i = 0; i < 4; ++i)
        #pragma unroll
        for (int j = 0; j < 4; ++j)
            acc[i][j] = (f32x4){0.f, 0.f, 0.f, 0.f};

    for (int k0 = 0; k0 < NC; k0 += 64) {
        stage_tile(Ag + k0, As, w, lane);
        stage_tile(Bg + k0, Bs, w, lane);
        __syncthreads();
        #pragma unroll
        for (int ks = 0; ks < 2; ++ks) {
            const int kc = (lane >> 4) + ks * 4;
            const int sw = (kc ^ (lane & 7)) * 8;
            short8v af[4], bf_[4];
            #pragma unroll
            for (int f = 0; f < 4; ++f) {
                af[f]  = *(const short8v*)(As + (wm * 64 + f * 16 + (lane & 15)) * 64 + sw);
                bf_[f] = *(const short8v*)(Bs + (wn * 64 + f * 16 + (lane & 15)) * 64 + sw);
            }
            #pragma unroll
            for (int fi = 0; fi < 4; ++fi)
                #pragma unroll
                for (int fj = 0; fj < 4; ++fj)
                    acc[fi][fj] = __builtin_amdgcn_mfma_f32_16x16x32_bf16(af[fi], bf_[fj], acc[fi][fj], 0, 0, 0);
        }
        __syncthreads();
    }

    const int b = n0 / HW;                       // 9216 % 128 == 0: no straddle
    const int hw0 = n0 - b * HW;
    const int ncol = hw0 + wn * 64 + (lane & 15);

    if constexpr (EPI == 0) {
        ushort* C = (ushort*)Cout;
        #pragma unroll
        for (int fi = 0; fi < 4; ++fi)
            #pragma unroll
            for (int r = 0; r < 4; ++r) {
                const int m = m0 + wm * 64 + fi * 16 + (lane >> 4) * 4 + r;
                const size_t base = ((size_t)b * Mtot + m) * HW + ncol;
                #pragma unroll
                for (int fj = 0; fj < 4; ++fj)
                    C[base + fj * 16] = f2bf(acc[fi][fj][r]);
            }
    } else {
        float* C = (float*)Cout;
        #pragma unroll
        for (int fi = 0; fi < 4; ++fi)
            #pragma unroll
            for (int r = 0; r < 4; ++r) {
                const int m = m0 + wm * 64 + fi * 16 + (lane >> 4) * 4 + r;
                const float bm = bias[m];
                const size_t base = ((size_t)b * NC + m) * HW + ncol;
                #pragma unroll
                for (int fj = 0; fj < 4; ++fj)
                    C[base + fj * 16] = acc[fi][fj][r] + bm + res[base + fj * 16];
            }
    }
}

// ---------------------------------------------------------------------------
// vsum[b][c][hw] = 3x3 zero-padded box sum of v channels (qkv 512..767), bf16
// ---------------------------------------------------------------------------
__global__ __launch_bounds__(256)
void boxsum_kernel(const ushort* __restrict__ qkv, ushort* __restrict__ vout)
{
    const int idx = blockIdx.x * 256 + threadIdx.x;
    const int hw = idx % HW;
    const int bc = idx / HW;
    const int b = bc / NC, c = bc - b * NC;
    const int ii = hw / W96, jj = hw - ii * W96;
    const ushort* p = qkv + ((size_t)b * 768 + 512 + c) * HW;
    float s = 0.f;
    #pragma unroll
    for (int dy = -1; dy <= 1; ++dy) {
        const int y = ii + dy;
        if (y < 0 || y >= H96) continue;
        #pragma unroll
        for (int dx = -1; dx <= 1; ++dx) {
            const int xc = jj + dx;
            if (xc < 0 || xc >= W96) continue;
            s += bf2f(p[(size_t)y * W96 + xc]);
        }
    }
    vout[(size_t)bc * HW + hw] = f2bf(s);
}

// ---------------------------------------------------------------------------
// Attention: block = (16-pixel strip, head, batch). Thread owns 2 softmax rows.
// Output written bf16 PIXEL-MAJOR: att[(b*HW+hw)][c] so gemm2 stages it directly.
// ---------------------------------------------------------------------------
__global__ __launch_bounds__(256)
void attn_kernel(const ushort* __restrict__ qkv, const ushort* __restrict__ vsum,
                 ushort* __restrict__ att)
{
    __shared__ float qs[HD][56];     // [n][dy*18+dx]
    __shared__ float kst[54][36];    // [dy*18+dx][m]
    __shared__ float vs[16][36];     // [px][m]

    const int t = threadIdx.x;
    const int strip = blockIdx.x;    // 0..575
    const int h = blockIdx.y;
    const int b = blockIdx.z;
    const int i0 = strip / 6;
    const int j0 = (strip - (strip / 6) * 6) * 16;

    const size_t qbase = ((size_t)b * 768 + h * HD) * HW;
    const size_t kbase = ((size_t)b * 768 + NC + h * HD) * HW;

    for (int e = t; e < HD * 54; e += 256) {
        const int n = e / 54, r = e - n * 54;
        const int dy = r / 18, dx = r - dy * 18;
        const int gi = i0 - 1 + dy, gj = j0 - 1 + dx;
        float qv = 0.f, kv = 0.f;
        if (gi >= 0 && gi < H96 && gj >= 0 && gj < W96) {
            const size_t off = (size_t)gi * W96 + gj;
            qv = bf2f(qkv[qbase + (size_t)n * HW + off]);
            kv = bf2f(qkv[kbase + (size_t)n * HW + off]);
        }
        qs[n][r] = qv;
        kst[r][n] = kv;
    }
    for (int e = t; e < 16 * HD; e += 256) {
        const int m = e >> 4, px = e & 15;
        vs[px][m] = bf2f(vsum[((size_t)b * NC + h * HD + m) * HW + (size_t)i0 * W96 + j0 + px]);
    }
    __syncthreads();

    const int px = t & 15;
    const int n0r = (t >> 4) * 2;

    float q0[9], q1[9];
    #pragma unroll
    for (int r9 = 0; r9 < 9; ++r9) {
        const int dy = r9 / 3, dj = r9 - dy * 3;
        const int si = dy * 18 + px + dj;
        q0[r9] = qs[n0r][si] * SCALE;
        q1[r9] = qs[n0r + 1][si] * SCALE;
    }

    float d0[32], d1[32];
    #pragma unroll
    for (int m = 0; m < 32; ++m) { d0[m] = 0.f; d1[m] = 0.f; }

    #pragma unroll
    for (int r9 = 0; r9 < 9; ++r9) {
        const int dy = r9 / 3, dj = r9 - dy * 3;
        const int si = dy * 18 + px + dj;
        const float4* kp = (const float4*)&kst[si][0];
        #pragma unroll
        for (int mb = 0; mb < 8; ++mb) {
            const float4 kv = kp[mb];
            d0[mb * 4 + 0] = fmaf(q0[r9], kv.x, d0[mb * 4 + 0]);
            d0[mb * 4 + 1] = fmaf(q0[r9], kv.y, d0[mb * 4 + 1]);
            d0[mb * 4 + 2] = fmaf(q0[r9], kv.z, d0[mb * 4 + 2]);
            d0[mb * 4 + 3] = fmaf(q0[r9], kv.w, d0[mb * 4 + 3]);
            d1[mb * 4 + 0] = fmaf(q1[r9], kv.x, d1[mb * 4 + 0]);
            d1[mb * 4 + 1] = fmaf(q1[r9], kv.y, d1[mb * 4 + 1]);
            d1[mb * 4 + 2] = fmaf(q1[r9], kv.z, d1[mb * 4 + 2]);
            d1[mb * 4 + 3] = fmaf(q1[r9], kv.w, d1[mb * 4 + 3]);
        }
    }

    float mx0 = d0[0], mx1 = d1[0];
    #pragma unroll
    for (int m = 1; m < 32; ++m) { mx0 = fmaxf(mx0, d0[m]); mx1 = fmaxf(mx1, d1[m]); }
    float s0 = 0.f, s1 = 0.f;
    #pragma unroll
    for (int m = 0; m < 32; ++m) {
        d0[m] = __expf(d0[m] - mx0); s0 += d0[m];
        d1[m] = __expf(d1[m] - mx1); s1 += d1[m];
    }

    float o0 = 0.f, o1 = 0.f;
    const float4* vp = (const float4*)&vs[px][0];
    #pragma unroll
    for (int mb = 0; mb < 8; ++mb) {
        const float4 vv = vp[mb];
        o0 += d0[mb * 4 + 0] * vv.x + d0[mb * 4 + 1] * vv.y + d0[mb * 4 + 2] * vv.z + d0[mb * 4 + 3] * vv.w;
        o1 += d1[mb * 4 + 0] * vv.x + d1[mb * 4 + 1] * vv.y + d1[mb * 4 + 2] * vv.z + d1[mb * 4 + 3] * vv.w;
    }
    o0 /= s0;
    o1 /= s1;

    // restage through LDS and write pixel-major bf16 (coalesced 64B runs)
    __syncthreads();
    float* ot = &qs[0][0];                       // reuse, 512 floats
    ot[px * 32 + n0r]     = o0;
    ot[px * 32 + n0r + 1] = o1;
    __syncthreads();
    {
        const int pxw = t >> 4, pr = t & 15;
        const float fx = ot[pxw * 32 + pr * 2];
        const float fy = ot[pxw * 32 + pr * 2 + 1];
        ushort2 u; u.x = f2bf(fx); u.y = f2bf(fy);
        *(ushort2*)(att + ((size_t)b * HW + (size_t)i0 * W96 + j0 + pxw) * NC + h * HD + pr * 2) = u;
    }
}

// ---------------------------------------------------------------------------
extern "C" void kernel_launch(void* const* d_in, const int* in_sizes, int n_in,
                              void* d_out, int out_size, void* d_ws, size_t ws_size,
                              hipStream_t stream)
{
    (void)in_sizes; (void)n_in; (void)out_size; (void)ws_size;
    const float* x     = (const float*)d_in[0];
    const float* w_qkv = (const float*)d_in[1];
    const float* w_out = (const float*)d_in[2];
    const float* b_out = (const float*)d_in[3];
    float* out = (float*)d_out;

    ushort* qkvb = (ushort*)d_ws;                      // [B][768][HW]   28.3 MB
    ushort* vsum = qkvb + (size_t)NB * 768 * HW;       // [B][256][HW]    9.4 MB
    ushort* attb = vsum + (size_t)NB * NC * HW;        // [B*HW][256]     9.4 MB
    ushort* xt   = attb + (size_t)NB * (size_t)HW * NC;// [B*HW][256]     9.4 MB
    ushort* wqb  = xt   + (size_t)NB * (size_t)HW * NC;// [768][256]
    ushort* wob  = wqb  + 768 * NC;                    // [256][256]

    // 0) dtype/layout prep
    x_to_bf16t<<<dim3(HW / 32, NC / 32, NB), 256, 0, stream>>>(x, xt);
    conv_bf16<<<dim3(768 * NC / 1024), 256, 0, stream>>>(w_qkv, wqb);
    conv_bf16<<<dim3(NC * NC / 1024), 256, 0, stream>>>(w_out, wob);
    // 1) qkv = w_qkv @ x   (bf16 MFMA)
    gemm_mfma<0><<<dim3(144, 6), 256, 0, stream>>>(wqb, xt, qkvb, nullptr, nullptr, 768);
    // 2) vsum = 3x3 box sum of v map
    boxsum_kernel<<<dim3(NB * NC * HW / 256), 256, 0, stream>>>(qkvb, vsum);
    // 3) local attention -> pixel-major bf16
    attn_kernel<<<dim3(576, NHEADS, NB), 256, 0, stream>>>(qkvb, vsum, attb);
    // 4) out = w_out @ att + b_out + x   (bf16 MFMA, fp32 epilogue)
    gemm_mfma<1><<<dim3(144, 2), 256, 0, stream>>>(wob, attb, out, b_out, x, 256);
}

// Round 4
// 195.432 us; speedup vs baseline: 1.6761x; 1.1209x over previous
//
#include <hip/hip_runtime.h>
#include <hip/hip_fp16.h>

#define H96 96
#define W96 96
#define HW  9216          // 96*96
#define NC  256
#define NB  2
#define NHEADS 8
#define HD  32
#define SCALE 0.17677669529663687f   // 1/sqrt(32)

typedef __attribute__((ext_vector_type(8))) short short8v;   // 8 bf16 (4 VGPRs)
typedef __attribute__((ext_vector_type(4))) float f32x4;

__device__ __forceinline__ ushort f2bf(float f) {
    unsigned u = __float_as_uint(f);
    u += 0x7FFFu + ((u >> 16) & 1u);          // round-to-nearest-even
    return (ushort)(u >> 16);
}
__device__ __forceinline__ float bf2f(ushort h) {
    return __uint_as_float(((unsigned)h) << 16);
}
__device__ __forceinline__ __half2 u2h2(unsigned u) {
    union { unsigned u; __half2 h; } c; c.u = u; return c.h;
}
// ROCm 7.2 hip_fp16.h lacks the __half2 overload of __hmax2 here; emit the
// packed max directly (one VOP3P instr, same as the intrinsic would).
__device__ __forceinline__ __half2 hmax2(__half2 a, __half2 b) {
    __half2 r;
    asm("v_pk_max_f16 %0, %1, %2" : "=v"(r) : "v"(a), "v"(b));
    return r;
}

// ---------------------------------------------------------------------------
// x [B][C][HW] fp32 -> xt [B][HW][C] bf16 (pixel-major, K-contiguous)
// ---------------------------------------------------------------------------
__global__ __launch_bounds__(256)
void x_to_bf16t(const float* __restrict__ x, ushort* __restrict__ xt)
{
    __shared__ float tile[32][33];
    const int t = threadIdx.x;
    const int hw0 = blockIdx.x * 32, c0 = blockIdx.y * 32, b = blockIdx.z;

    const int r = t >> 3, cc = (t & 7) * 4;
    const float4 v = *(const float4*)(x + ((size_t)b * NC + c0 + r) * HW + hw0 + cc);
    tile[r][cc + 0] = v.x; tile[r][cc + 1] = v.y; tile[r][cc + 2] = v.z; tile[r][cc + 3] = v.w;
    __syncthreads();

    const int hwr = t >> 3, c4 = (t & 7) * 4;
    ushort4 o;
    o.x = f2bf(tile[c4 + 0][hwr]);
    o.y = f2bf(tile[c4 + 1][hwr]);
    o.z = f2bf(tile[c4 + 2][hwr]);
    o.w = f2bf(tile[c4 + 3][hwr]);
    *(ushort4*)(xt + ((size_t)b * HW + hw0 + hwr) * NC + c0 + c4) = o;
}

// ---------------------------------------------------------------------------
// fp32 -> bf16 elementwise (weights). n must be multiple of 1024.
// ---------------------------------------------------------------------------
__global__ __launch_bounds__(256)
void conv_bf16(const float* __restrict__ w, ushort* __restrict__ o)
{
    const int i = (blockIdx.x * 256 + threadIdx.x) * 4;
    const float4 v = *(const float4*)(w + i);
    ushort4 u;
    u.x = f2bf(v.x); u.y = f2bf(v.y); u.z = f2bf(v.z); u.w = f2bf(v.w);
    *(ushort4*)(o + i) = u;
}

// ---------------------------------------------------------------------------
// MFMA GEMM: C[b][m][hw] = sum_c A[m][c] * Bt[(b*HW+hw)][c]
// 128x128 tile, BK=64, 4 waves (2x2). global_load_lds w=16, XOR-swizzled LDS.
// ---------------------------------------------------------------------------
__device__ __forceinline__ void stage_tile(const ushort* __restrict__ g, ushort* lds,
                                           int w, int lane)
{
    const int lr  = lane >> 3;                  // row within 8-row chunk
    const int swz = ((lane & 7) ^ lr) * 8;      // pre-swizzled k-chunk (ushort units)
    #pragma unroll
    for (int ii = 0; ii < 4; ++ii) {
        const int rowbase = w * 32 + ii * 8;
        const ushort* src = g + (size_t)(rowbase + lr) * NC + swz;
        __builtin_amdgcn_global_load_lds((const __attribute__((address_space(1))) void*)src,
                                         (__attribute__((address_space(3))) void*)(lds + rowbase * 64),
                                         16, 0, 0);
    }
}

template<int EPI>
__global__ __launch_bounds__(256)
void gemm_mfma(const ushort* __restrict__ A, const ushort* __restrict__ Bt,
               void* __restrict__ Cout, const float* __restrict__ bias,
               const float* __restrict__ res, int Mtot)
{
    __shared__ __align__(16) ushort As[128 * 64];
    __shared__ __align__(16) ushort Bs[128 * 64];

    const int t = threadIdx.x;
    const int lane = t & 63, w = t >> 6;
    const int wm = w >> 1, wn = w & 1;
    const int n0 = blockIdx.x * 128;
    const int m0 = blockIdx.y * 128;

    const ushort* Ag = A + (size_t)m0 * NC;
    const ushort* Bg = Bt + (size_t)n0 * NC;

    f32x4 acc[4][4];
    #pragma unroll
    for (int i = 0; i < 4; ++i)
        #pragma unroll
        for (int j = 0; j < 4; ++j)
            acc[i][j] = (f32x4){0.f, 0.f, 0.f, 0.f};

    for (int k0 = 0; k0 < NC; k0 += 64) {
        stage_tile(Ag + k0, As, w, lane);
        stage_tile(Bg + k0, Bs, w, lane);
        __syncthreads();
        #pragma unroll
        for (int ks = 0; ks < 2; ++ks) {
            const int kc = (lane >> 4) + ks * 4;
            const int sw = (kc ^ (lane & 7)) * 8;
            short8v af[4], bf_[4];
            #pragma unroll
            for (int f = 0; f < 4; ++f) {
                af[f]  = *(const short8v*)(As + (wm * 64 + f * 16 + (lane & 15)) * 64 + sw);
                bf_[f] = *(const short8v*)(Bs + (wn * 64 + f * 16 + (lane & 15)) * 64 + sw);
            }
            #pragma unroll
            for (int fi = 0; fi < 4; ++fi)
                #pragma unroll
                for (int fj = 0; fj < 4; ++fj)
                    acc[fi][fj] = __builtin_amdgcn_mfma_f32_16x16x32_bf16(af[fi], bf_[fj], acc[fi][fj], 0, 0, 0);
        }
        __syncthreads();
    }

    const int b = n0 / HW;
    const int hw0 = n0 - b * HW;
    const int ncol = hw0 + wn * 64 + (lane & 15);

    if constexpr (EPI == 0) {
        ushort* C = (ushort*)Cout;
        #pragma unroll
        for (int fi = 0; fi < 4; ++fi)
            #pragma unroll
            for (int r = 0; r < 4; ++r) {
                const int m = m0 + wm * 64 + fi * 16 + (lane >> 4) * 4 + r;
                const size_t base = ((size_t)b * Mtot + m) * HW + ncol;
                #pragma unroll
                for (int fj = 0; fj < 4; ++fj)
                    C[base + fj * 16] = f2bf(acc[fi][fj][r]);
            }
    } else {
        float* C = (float*)Cout;
        #pragma unroll
        for (int fi = 0; fi < 4; ++fi)
            #pragma unroll
            for (int r = 0; r < 4; ++r) {
                const int m = m0 + wm * 64 + fi * 16 + (lane >> 4) * 4 + r;
                const float bm = bias[m];
                const size_t base = ((size_t)b * NC + m) * HW + ncol;
                #pragma unroll
                for (int fj = 0; fj < 4; ++fj)
                    C[base + fj * 16] = acc[fi][fj][r] + bm + res[base + fj * 16];
            }
    }
}

// ---------------------------------------------------------------------------
// vsum = 3x3 zero-padded box sum of v channels. 1 thread = 8 pixels, separable.
// ---------------------------------------------------------------------------
__global__ __launch_bounds__(256)
void boxsum_kernel(const ushort* __restrict__ qkv, ushort* __restrict__ vout)
{
    const int idx = blockIdx.x * 256 + threadIdx.x;   // NB*NC*HW/8 total
    const int jblk = idx % 12;
    const int rest = idx / 12;
    const int i = rest % H96;
    const int bc = rest / H96;                         // b*256+c
    const int b = bc >> 8, c = bc & 255;
    const ushort* p = qkv + ((size_t)b * 768 + 512 + c) * HW;
    const int j0 = jblk * 8;

    float vert[10];
    #pragma unroll
    for (int jj = 0; jj < 10; ++jj) vert[jj] = 0.f;

    #pragma unroll
    for (int dy = -1; dy <= 1; ++dy) {
        const int r = i + dy;
        if (r < 0 || r >= H96) continue;
        const ushort* row = p + (size_t)r * W96 + j0;
        const short8v v = *(const short8v*)row;
        #pragma unroll
        for (int jj = 0; jj < 8; ++jj) vert[jj + 1] += bf2f((ushort)v[jj]);
        if (j0 > 0)      vert[0] += bf2f(row[-1]);
        if (j0 + 8 < W96) vert[9] += bf2f(row[8]);
    }

    short8v o;
    #pragma unroll
    for (int jj = 0; jj < 8; ++jj)
        o[jj] = (short)f2bf(vert[jj] + vert[jj + 1] + vert[jj + 2]);
    *(short8v*)(vout + (size_t)bc * HW + (size_t)i * W96 + j0) = o;
}

// ---------------------------------------------------------------------------
// Attention: block = (16-px strip, head, batch). Thread owns 2 softmax rows.
// Dots/softmax/PV in packed __half2 (m-pairs). K,vsum staged f16 in LDS with
// 56-ushort row stride (112 B: 16B-aligned, 28-word bank step -> 2-way max).
// ---------------------------------------------------------------------------
__global__ __launch_bounds__(256, 1)
void attn_kernel(const ushort* __restrict__ qkv, const ushort* __restrict__ vsum,
                 ushort* __restrict__ att)
{
    __shared__ float  qs[HD][56];      // [n][dy*18+dx] f32
    __shared__ ushort kst[54][56];     // [dy*18+dx][m] f16
    __shared__ ushort vs[16][56];      // [px][m] f16

    const int t = threadIdx.x;
    const int strip = blockIdx.x;      // 0..575
    const int h = blockIdx.y;
    const int b = blockIdx.z;
    const int i0 = strip / 6;
    const int j0 = (strip - (strip / 6) * 6) * 16;

    const size_t qbase = ((size_t)b * 768 + h * HD) * HW;
    const size_t kbase = ((size_t)b * 768 + NC + h * HD) * HW;

    for (int e = t; e < HD * 54; e += 256) {
        const int n = e / 54, r = e - n * 54;
        const int dy = r / 18, dx = r - dy * 18;
        const int gi = i0 - 1 + dy, gj = j0 - 1 + dx;
        float qv = 0.f, kv = 0.f;
        if (gi >= 0 && gi < H96 && gj >= 0 && gj < W96) {
            const size_t off = (size_t)gi * W96 + gj;
            qv = bf2f(qkv[qbase + (size_t)n * HW + off]);
            kv = bf2f(qkv[kbase + (size_t)n * HW + off]);
        }
        qs[n][r] = qv;
        kst[r][n] = __half_as_ushort(__float2half_rn(kv));
    }
    for (int e = t; e < 16 * HD; e += 256) {
        const int m = e >> 4, px = e & 15;
        const float vv = bf2f(vsum[((size_t)b * NC + h * HD + m) * HW + (size_t)i0 * W96 + j0 + px]);
        vs[px][m] = __half_as_ushort(__float2half_rn(vv));
    }
    __syncthreads();

    const int px = t & 15;
    const int n0r = (t >> 4) * 2;

    __half2 qh0[9], qh1[9];
    int sidx[9];
    #pragma unroll
    for (int r9 = 0; r9 < 9; ++r9) {
        const int dy = r9 / 3, dj = r9 - dy * 3;
        const int si = dy * 18 + px + dj;
        sidx[r9] = si;
        qh0[r9] = __float2half2_rn(qs[n0r][si] * SCALE);
        qh1[r9] = __float2half2_rn(qs[n0r + 1][si] * SCALE);
    }

    __half2 d0[16], d1[16];
    const __half2 z2 = __float2half2_rn(0.f);
    #pragma unroll
    for (int j = 0; j < 16; ++j) { d0[j] = z2; d1[j] = z2; }

    #pragma unroll
    for (int r9 = 0; r9 < 9; ++r9) {
        const uint4* kp = (const uint4*)&kst[sidx[r9]][0];
        #pragma unroll
        for (int mb = 0; mb < 4; ++mb) {
            const uint4 kq = kp[mb];
            const __half2 k0 = u2h2(kq.x), k1 = u2h2(kq.y), k2 = u2h2(kq.z), k3 = u2h2(kq.w);
            d0[mb * 4 + 0] = __hfma2(qh0[r9], k0, d0[mb * 4 + 0]);
            d0[mb * 4 + 1] = __hfma2(qh0[r9], k1, d0[mb * 4 + 1]);
            d0[mb * 4 + 2] = __hfma2(qh0[r9], k2, d0[mb * 4 + 2]);
            d0[mb * 4 + 3] = __hfma2(qh0[r9], k3, d0[mb * 4 + 3]);
            d1[mb * 4 + 0] = __hfma2(qh1[r9], k0, d1[mb * 4 + 0]);
            d1[mb * 4 + 1] = __hfma2(qh1[r9], k1, d1[mb * 4 + 1]);
            d1[mb * 4 + 2] = __hfma2(qh1[r9], k2, d1[mb * 4 + 2]);
            d1[mb * 4 + 3] = __hfma2(qh1[r9], k3, d1[mb * 4 + 3]);
        }
    }

    // softmax over m (local to thread)
    __half2 m0 = d0[0], m1 = d1[0];
    #pragma unroll
    for (int j = 1; j < 16; ++j) { m0 = hmax2(m0, d0[j]); m1 = hmax2(m1, d1[j]); }
    const __half2 mx0 = __float2half2_rn(fmaxf(__low2float(m0), __high2float(m0)));
    const __half2 mx1 = __float2half2_rn(fmaxf(__low2float(m1), __high2float(m1)));

    __half2 s0 = z2, s1 = z2;
    #pragma unroll
    for (int j = 0; j < 16; ++j) {
        d0[j] = h2exp(__hsub2(d0[j], mx0)); s0 = __hadd2(s0, d0[j]);
        d1[j] = h2exp(__hsub2(d1[j], mx1)); s1 = __hadd2(s1, d1[j]);
    }
    const float den0 = __low2float(s0) + __high2float(s0);
    const float den1 = __low2float(s1) + __high2float(s1);

    // PV with vsum (f16 packed)
    __half2 o0 = z2, o1 = z2;
    const uint4* vp = (const uint4*)&vs[px][0];
    #pragma unroll
    for (int mb = 0; mb < 4; ++mb) {
        const uint4 vq = vp[mb];
        const __half2 v0 = u2h2(vq.x), v1 = u2h2(vq.y), v2 = u2h2(vq.z), v3 = u2h2(vq.w);
        o0 = __hfma2(d0[mb * 4 + 0], v0, o0); o0 = __hfma2(d0[mb * 4 + 1], v1, o0);
        o0 = __hfma2(d0[mb * 4 + 2], v2, o0); o0 = __hfma2(d0[mb * 4 + 3], v3, o0);
        o1 = __hfma2(d1[mb * 4 + 0], v0, o1); o1 = __hfma2(d1[mb * 4 + 1], v1, o1);
        o1 = __hfma2(d1[mb * 4 + 2], v2, o1); o1 = __hfma2(d1[mb * 4 + 3], v3, o1);
    }
    const float fo0 = (__low2float(o0) + __high2float(o0)) / den0;
    const float fo1 = (__low2float(o1) + __high2float(o1)) / den1;

    // restage through LDS and write pixel-major bf16
    __syncthreads();
    float* ot = &qs[0][0];
    ot[px * 32 + n0r]     = fo0;
    ot[px * 32 + n0r + 1] = fo1;
    __syncthreads();
    {
        const int pxw = t >> 4, pr = t & 15;
        const float fx = ot[pxw * 32 + pr * 2];
        const float fy = ot[pxw * 32 + pr * 2 + 1];
        ushort2 u; u.x = f2bf(fx); u.y = f2bf(fy);
        *(ushort2*)(att + ((size_t)b * HW + (size_t)i0 * W96 + j0 + pxw) * NC + h * HD + pr * 2) = u;
    }
}

// ---------------------------------------------------------------------------
extern "C" void kernel_launch(void* const* d_in, const int* in_sizes, int n_in,
                              void* d_out, int out_size, void* d_ws, size_t ws_size,
                              hipStream_t stream)
{
    (void)in_sizes; (void)n_in; (void)out_size; (void)ws_size;
    const float* x     = (const float*)d_in[0];
    const float* w_qkv = (const float*)d_in[1];
    const float* w_out = (const float*)d_in[2];
    const float* b_out = (const float*)d_in[3];
    float* out = (float*)d_out;

    ushort* qkvb = (ushort*)d_ws;                      // [B][768][HW]
    ushort* vsum = qkvb + (size_t)NB * 768 * HW;       // [B][256][HW]
    ushort* attb = vsum + (size_t)NB * NC * HW;        // [B*HW][256]
    ushort* xt   = attb + (size_t)NB * (size_t)HW * NC;// [B*HW][256]
    ushort* wqb  = xt   + (size_t)NB * (size_t)HW * NC;// [768][256]
    ushort* wob  = wqb  + 768 * NC;                    // [256][256]

    x_to_bf16t<<<dim3(HW / 32, NC / 32, NB), 256, 0, stream>>>(x, xt);
    conv_bf16<<<dim3(768 * NC / 1024), 256, 0, stream>>>(w_qkv, wqb);
    conv_bf16<<<dim3(NC * NC / 1024), 256, 0, stream>>>(w_out, wob);
    gemm_mfma<0><<<dim3(144, 6), 256, 0, stream>>>(wqb, xt, qkvb, nullptr, nullptr, 768);
    boxsum_kernel<<<dim3(NB * NC * HW / 8 / 256), 256, 0, stream>>>(qkvb, vsum);
    attn_kernel<<<dim3(576, NHEADS, NB), 256, 0, stream>>>(qkvb, vsum, attb);
    gemm_mfma<1><<<dim3(144, 2), 256, 0, stream>>>(wob, attb, out, b_out, x, 256);
}

// Round 5
// 176.676 us; speedup vs baseline: 1.8541x; 1.1062x over previous
//
#include <hip/hip_runtime.h>
#include <hip/hip_fp16.h>

#define H96 96
#define W96 96
#define HW  9216          // 96*96
#define NC  256
#define NB  2
#define NHEADS 8
#define HD  32
#define SCALE 0.17677669529663687f   // 1/sqrt(32)

typedef __attribute__((ext_vector_type(8))) short short8v;   // 8 bf16 (4 VGPRs)
typedef __attribute__((ext_vector_type(4))) float f32x4;

__device__ __forceinline__ ushort f2bf(float f) {
    unsigned u = __float_as_uint(f);
    u += 0x7FFFu + ((u >> 16) & 1u);          // round-to-nearest-even
    return (ushort)(u >> 16);
}
__device__ __forceinline__ float bf2f(ushort h) {
    return __uint_as_float(((unsigned)h) << 16);
}
__device__ __forceinline__ __half2 u2h2(unsigned u) {
    union { unsigned u; __half2 h; } c; c.u = u; return c.h;
}
// ROCm 7.2 hip_fp16.h lacks __half2 overloads of these on this path; emit
// the packed ops directly (single VOP3P instrs).
__device__ __forceinline__ __half2 hmax2(__half2 a, __half2 b) {
    __half2 r;
    asm("v_pk_max_f16 %0, %1, %2" : "=v"(r) : "v"(a), "v"(b));
    return r;
}
__device__ __forceinline__ unsigned pkmul_u(unsigned a, __half2 s) {
    unsigned r;
    asm("v_pk_mul_f16 %0, %1, %2" : "=v"(r) : "v"(a), "v"(s));
    return r;
}

// ---------------------------------------------------------------------------
// x [B][C][HW] fp32 -> xt [B][HW][C] bf16 (pixel-major, K-contiguous)
// ---------------------------------------------------------------------------
__global__ __launch_bounds__(256)
void x_to_bf16t(const float* __restrict__ x, ushort* __restrict__ xt)
{
    __shared__ float tile[32][33];
    const int t = threadIdx.x;
    const int hw0 = blockIdx.x * 32, c0 = blockIdx.y * 32, b = blockIdx.z;

    const int r = t >> 3, cc = (t & 7) * 4;
    const float4 v = *(const float4*)(x + ((size_t)b * NC + c0 + r) * HW + hw0 + cc);
    tile[r][cc + 0] = v.x; tile[r][cc + 1] = v.y; tile[r][cc + 2] = v.z; tile[r][cc + 3] = v.w;
    __syncthreads();

    const int hwr = t >> 3, c4 = (t & 7) * 4;
    ushort4 o;
    o.x = f2bf(tile[c4 + 0][hwr]);
    o.y = f2bf(tile[c4 + 1][hwr]);
    o.z = f2bf(tile[c4 + 2][hwr]);
    o.w = f2bf(tile[c4 + 3][hwr]);
    *(ushort4*)(xt + ((size_t)b * HW + hw0 + hwr) * NC + c0 + c4) = o;
}

// ---------------------------------------------------------------------------
// fp32 -> bf16 elementwise (weights). n must be multiple of 1024.
// ---------------------------------------------------------------------------
__global__ __launch_bounds__(256)
void conv_bf16(const float* __restrict__ w, ushort* __restrict__ o)
{
    const int i = (blockIdx.x * 256 + threadIdx.x) * 4;
    const float4 v = *(const float4*)(w + i);
    ushort4 u;
    u.x = f2bf(v.x); u.y = f2bf(v.y); u.z = f2bf(v.z); u.w = f2bf(v.w);
    *(ushort4*)(o + i) = u;
}

// ---------------------------------------------------------------------------
// MFMA GEMM: acc[m][hw] = sum_c A[m][c] * Bt[pixel][c]   (A,Bt bf16)
// 128x128 tile, BK=64, 4 waves (2x2). global_load_lds w=16, XOR-swizzled LDS.
// EPI=0: write f16 PIXEL-MAJOR [pixel][Mtot] via LDS-transposed epilogue.
// EPI=1: write fp32 m-major [b][256][hw] + bias + residual.
// ---------------------------------------------------------------------------
__device__ __forceinline__ void stage_tile(const ushort* __restrict__ g, ushort* lds,
                                           int w, int lane)
{
    const int lr  = lane >> 3;                  // row within 8-row chunk
    const int swz = ((lane & 7) ^ lr) * 8;      // pre-swizzled k-chunk (ushort units)
    #pragma unroll
    for (int ii = 0; ii < 4; ++ii) {
        const int rowbase = w * 32 + ii * 8;
        const ushort* src = g + (size_t)(rowbase + lr) * NC + swz;
        __builtin_amdgcn_global_load_lds((const __attribute__((address_space(1))) void*)src,
                                         (__attribute__((address_space(3))) void*)(lds + rowbase * 64),
                                         16, 0, 0);
    }
}

template<int EPI>
__global__ __launch_bounds__(256)
void gemm_mfma(const ushort* __restrict__ A, const ushort* __restrict__ Bt,
               void* __restrict__ Cout, const float* __restrict__ bias,
               const float* __restrict__ res, int Mtot)
{
    __shared__ __align__(16) ushort smem[128 * 136];   // main: As|Bs; epi0: transpose
    ushort* As = smem;
    ushort* Bs = smem + 128 * 64;

    const int t = threadIdx.x;
    const int lane = t & 63, w = t >> 6;
    const int wm = w >> 1, wn = w & 1;
    const int n0 = blockIdx.x * 128;
    const int m0 = blockIdx.y * 128;

    const ushort* Ag = A + (size_t)m0 * NC;
    const ushort* Bg = Bt + (size_t)n0 * NC;

    f32x4 acc[4][4];
    #pragma unroll
    for (int i = 0; i < 4; ++i)
        #pragma unroll
        for (int j = 0; j < 4; ++j)
            acc[i][j] = (f32x4){0.f, 0.f, 0.f, 0.f};

    for (int k0 = 0; k0 < NC; k0 += 64) {
        stage_tile(Ag + k0, As, w, lane);
        stage_tile(Bg + k0, Bs, w, lane);
        __syncthreads();
        #pragma unroll
        for (int ks = 0; ks < 2; ++ks) {
            const int kc = (lane >> 4) + ks * 4;
            const int sw = (kc ^ (lane & 7)) * 8;
            short8v af[4], bf_[4];
            #pragma unroll
            for (int f = 0; f < 4; ++f) {
                af[f]  = *(const short8v*)(As + (wm * 64 + f * 16 + (lane & 15)) * 64 + sw);
                bf_[f] = *(const short8v*)(Bs + (wn * 64 + f * 16 + (lane & 15)) * 64 + sw);
            }
            #pragma unroll
            for (int fi = 0; fi < 4; ++fi)
                #pragma unroll
                for (int fj = 0; fj < 4; ++fj)
                    acc[fi][fj] = __builtin_amdgcn_mfma_f32_16x16x32_bf16(af[fi], bf_[fj], acc[fi][fj], 0, 0, 0);
        }
        __syncthreads();
    }

    const int b = n0 / HW;                       // 9216 % 128 == 0: no straddle
    const int hw0 = n0 - b * HW;

    if constexpr (EPI == 0) {
        // acc -> LDS [hw_local][m_local] (stride 136: 272B rows, 16B-aligned)
        #pragma unroll
        for (int fi = 0; fi < 4; ++fi)
            #pragma unroll
            for (int fj = 0; fj < 4; ++fj) {
                const int hwl = wn * 64 + fj * 16 + (lane & 15);
                const int ml  = wm * 64 + fi * 16 + (lane >> 4) * 4;
                ushort4 v4;
                v4.x = __half_as_ushort(__float2half_rn(acc[fi][fj][0]));
                v4.y = __half_as_ushort(__float2half_rn(acc[fi][fj][1]));
                v4.z = __half_as_ushort(__float2half_rn(acc[fi][fj][2]));
                v4.w = __half_as_ushort(__float2half_rn(acc[fi][fj][3]));
                *(ushort4*)(smem + hwl * 136 + ml) = v4;
            }
        __syncthreads();
        ushort* C = (ushort*)Cout;
        #pragma unroll
        for (int it = 0; it < 8; ++it) {
            const int cid = it * 256 + t;
            const int hwl = cid >> 4, mc = (cid & 15) * 8;
            const uint4 v = *(const uint4*)(smem + hwl * 136 + mc);
            *(uint4*)(C + ((size_t)b * HW + hw0 + hwl) * (size_t)Mtot + m0 + mc) = v;
        }
    } else {
        float* C = (float*)Cout;
        const int ncol = hw0 + wn * 64 + (lane & 15);
        #pragma unroll
        for (int fi = 0; fi < 4; ++fi)
            #pragma unroll
            for (int r = 0; r < 4; ++r) {
                const int m = m0 + wm * 64 + fi * 16 + (lane >> 4) * 4 + r;
                const float bm = bias[m];
                const size_t base = ((size_t)b * NC + m) * HW + ncol;
                #pragma unroll
                for (int fj = 0; fj < 4; ++fj)
                    C[base + fj * 16] = acc[fi][fj][r] + bm + res[base + fj * 16];
            }
    }
}

// ---------------------------------------------------------------------------
// Attention. qkvp: f16 pixel-major [b][hw][768] (q 0..255, k 256..511, v 512..767).
// Block = (16-px strip, head, batch); thread owns 2 softmax rows of 1 pixel.
// vsum (3x3 box sum of v) computed in-kernel from the staged v halo.
// Strip index XCD-swizzled so vertically-adjacent strips share an XCD's L2.
// ---------------------------------------------------------------------------
__global__ __launch_bounds__(256)
void attn_px(const ushort* __restrict__ qkvp, ushort* __restrict__ att)
{
    __shared__ ushort qh[54 * 40];   // [halo px][32 ch] f16 (q, pre-scaled)
    __shared__ ushort kh[54 * 40];
    __shared__ ushort vh[54 * 40];
    __shared__ ushort vs[16 * 40];   // [center px][32 m] f16 box-sum
    __shared__ float  ot[512];       // output restage

    const int t = threadIdx.x;
    const int sraw = blockIdx.x;                       // 0..575
    const int strip = (sraw & 7) * 72 + (sraw >> 3);   // XCD-chunked (bijective)
    const int h = blockIdx.y;
    const int b = blockIdx.z;
    const int i0 = strip / 6;
    const int j0 = (strip - (strip / 6) * 6) * 16;

    const ushort* P = qkvp + (size_t)b * HW * 768;
    const int qo = h * HD, ko = NC + h * HD, vo = 2 * NC + h * HD;
    const __half2 sc2 = __float2half2_rn(SCALE);

    // ---- stage q/k/v halos: 54 px x 4 chunks of 16B each ----
    if (t < 216) {
        const int px = t >> 2, c = (t & 3) * 8;
        const int dy = px / 18, dx = px - dy * 18;
        const int gi = i0 - 1 + dy, gj = j0 - 1 + dx;
        uint4 qv = {0, 0, 0, 0}, kv = {0, 0, 0, 0}, vv = {0, 0, 0, 0};
        if (gi >= 0 && gi < H96 && gj >= 0 && gj < W96) {
            const ushort* pp = P + ((size_t)gi * W96 + gj) * 768;
            qv = *(const uint4*)(pp + qo + c);
            kv = *(const uint4*)(pp + ko + c);
            vv = *(const uint4*)(pp + vo + c);
        }
        qv.x = pkmul_u(qv.x, sc2); qv.y = pkmul_u(qv.y, sc2);
        qv.z = pkmul_u(qv.z, sc2); qv.w = pkmul_u(qv.w, sc2);
        *(uint4*)(qh + px * 40 + c) = qv;
        *(uint4*)(kh + px * 40 + c) = kv;
        *(uint4*)(vh + px * 40 + c) = vv;
    }
    __syncthreads();

    // ---- vsum: 3x3 box sum over halo, all 256 threads (16 px x 16 half2) ----
    {
        const int px = t >> 4, m2 = (t & 15) * 2;
        __half2 s = __float2half2_rn(0.f);
        #pragma unroll
        for (int dy = 0; dy < 3; ++dy)
            #pragma unroll
            for (int dx = 0; dx < 3; ++dx)
                s = __hadd2(s, *(const __half2*)(vh + (dy * 18 + px + dx) * 40 + m2));
        *(__half2*)(vs + px * 40 + m2) = s;
    }

    // ---- q fragments for this thread's 2 rows ----
    const int px = t & 15;
    const int n0r = (t >> 4) * 2;

    __half2 q0[9], q1[9];
    int sidx[9];
    #pragma unroll
    for (int r9 = 0; r9 < 9; ++r9) {
        const int dy = r9 / 3, dj = r9 - dy * 3;
        const int si = dy * 18 + px + dj;
        sidx[r9] = si;
        const __half2 qq = *(const __half2*)(qh + si * 40 + n0r);   // [n0r, n0r+1]
        q0[r9] = __halves2half2(__low2half(qq), __low2half(qq));
        q1[r9] = __halves2half2(__high2half(qq), __high2half(qq));
    }

    // ---- dots ----
    __half2 d0[16], d1[16];
    const __half2 z2 = __float2half2_rn(0.f);
    #pragma unroll
    for (int j = 0; j < 16; ++j) { d0[j] = z2; d1[j] = z2; }

    #pragma unroll
    for (int r9 = 0; r9 < 9; ++r9) {
        const uint4* kp = (const uint4*)(kh + sidx[r9] * 40);
        #pragma unroll
        for (int mb = 0; mb < 4; ++mb) {
            const uint4 kq = kp[mb];
            const __half2 k0 = u2h2(kq.x), k1 = u2h2(kq.y), k2 = u2h2(kq.z), k3 = u2h2(kq.w);
            d0[mb * 4 + 0] = __hfma2(q0[r9], k0, d0[mb * 4 + 0]);
            d0[mb * 4 + 1] = __hfma2(q0[r9], k1, d0[mb * 4 + 1]);
            d0[mb * 4 + 2] = __hfma2(q0[r9], k2, d0[mb * 4 + 2]);
            d0[mb * 4 + 3] = __hfma2(q0[r9], k3, d0[mb * 4 + 3]);
            d1[mb * 4 + 0] = __hfma2(q1[r9], k0, d1[mb * 4 + 0]);
            d1[mb * 4 + 1] = __hfma2(q1[r9], k1, d1[mb * 4 + 1]);
            d1[mb * 4 + 2] = __hfma2(q1[r9], k2, d1[mb * 4 + 2]);
            d1[mb * 4 + 3] = __hfma2(q1[r9], k3, d1[mb * 4 + 3]);
        }
    }
    __syncthreads();   // vs complete (written pre-dots), before PV reads it

    // ---- softmax over m (fully thread-local) ----
    __half2 m0 = d0[0], m1 = d1[0];
    #pragma unroll
    for (int j = 1; j < 16; ++j) { m0 = hmax2(m0, d0[j]); m1 = hmax2(m1, d1[j]); }
    const __half2 mx0 = __float2half2_rn(fmaxf(__low2float(m0), __high2float(m0)));
    const __half2 mx1 = __float2half2_rn(fmaxf(__low2float(m1), __high2float(m1)));

    __half2 s0 = z2, s1 = z2;
    #pragma unroll
    for (int j = 0; j < 16; ++j) {
        d0[j] = h2exp(__hsub2(d0[j], mx0)); s0 = __hadd2(s0, d0[j]);
        d1[j] = h2exp(__hsub2(d1[j], mx1)); s1 = __hadd2(s1, d1[j]);
    }
    const float den0 = __low2float(s0) + __high2float(s0);
    const float den1 = __low2float(s1) + __high2float(s1);

    // ---- PV with vsum ----
    __half2 o0 = z2, o1 = z2;
    const uint4* vp = (const uint4*)(vs + px * 40);
    #pragma unroll
    for (int mb = 0; mb < 4; ++mb) {
        const uint4 vq = vp[mb];
        const __half2 v0 = u2h2(vq.x), v1 = u2h2(vq.y), v2 = u2h2(vq.z), v3 = u2h2(vq.w);
        o0 = __hfma2(d0[mb * 4 + 0], v0, o0); o0 = __hfma2(d0[mb * 4 + 1], v1, o0);
        o0 = __hfma2(d0[mb * 4 + 2], v2, o0); o0 = __hfma2(d0[mb * 4 + 3], v3, o0);
        o1 = __hfma2(d1[mb * 4 + 0], v0, o1); o1 = __hfma2(d1[mb * 4 + 1], v1, o1);
        o1 = __hfma2(d1[mb * 4 + 2], v2, o1); o1 = __hfma2(d1[mb * 4 + 3], v3, o1);
    }
    const float fo0 = (__low2float(o0) + __high2float(o0)) / den0;
    const float fo1 = (__low2float(o1) + __high2float(o1)) / den1;

    // ---- restage and write pixel-major bf16 ----
    ot[px * 32 + n0r]     = fo0;
    ot[px * 32 + n0r + 1] = fo1;
    __syncthreads();
    {
        const int pxw = t >> 4, pr = t & 15;
        const float fx = ot[pxw * 32 + pr * 2];
        const float fy = ot[pxw * 32 + pr * 2 + 1];
        ushort2 u; u.x = f2bf(fx); u.y = f2bf(fy);
        *(ushort2*)(att + ((size_t)b * HW + (size_t)i0 * W96 + j0 + pxw) * NC + h * HD + pr * 2) = u;
    }
}

// ---------------------------------------------------------------------------
extern "C" void kernel_launch(void* const* d_in, const int* in_sizes, int n_in,
                              void* d_out, int out_size, void* d_ws, size_t ws_size,
                              hipStream_t stream)
{
    (void)in_sizes; (void)n_in; (void)out_size; (void)ws_size;
    const float* x     = (const float*)d_in[0];
    const float* w_qkv = (const float*)d_in[1];
    const float* w_out = (const float*)d_in[2];
    const float* b_out = (const float*)d_in[3];
    float* out = (float*)d_out;

    ushort* qkvp = (ushort*)d_ws;                        // [B*HW][768] f16  28.3 MB
    ushort* attb = qkvp + (size_t)NB * HW * 768;         // [B*HW][256] bf16  9.4 MB
    ushort* xt   = attb + (size_t)NB * HW * NC;          // [B*HW][256] bf16  9.4 MB
    ushort* wqb  = xt   + (size_t)NB * HW * NC;          // [768][256] bf16
    ushort* wob  = wqb  + 768 * NC;                      // [256][256] bf16

    x_to_bf16t<<<dim3(HW / 32, NC / 32, NB), 256, 0, stream>>>(x, xt);
    conv_bf16<<<dim3(768 * NC / 1024), 256, 0, stream>>>(w_qkv, wqb);
    conv_bf16<<<dim3(NC * NC / 1024), 256, 0, stream>>>(w_out, wob);
    // qkv = w_qkv @ x -> f16 pixel-major
    gemm_mfma<0><<<dim3(144, 6), 256, 0, stream>>>(wqb, xt, qkvp, nullptr, nullptr, 768);
    // local attention (fused box-sum) -> bf16 pixel-major
    attn_px<<<dim3(576, NHEADS, NB), 256, 0, stream>>>(qkvp, attb);
    // out = w_out @ att + b_out + x (fp32 m-major)
    gemm_mfma<1><<<dim3(144, 2), 256, 0, stream>>>(wob, attb, out, b_out, x, 256);
}

// Round 6
// 171.756 us; speedup vs baseline: 1.9072x; 1.0286x over previous
//
#include <hip/hip_runtime.h>
#include <hip/hip_fp16.h>

#define H96 96
#define W96 96
#define HW  9216          // 96*96
#define NC  256
#define NB  2
#define NHEADS 8
#define HD  32
#define SCALE 0.17677669529663687f   // 1/sqrt(32)

typedef __attribute__((ext_vector_type(8))) short short8v;   // 8 bf16 (4 VGPRs)
typedef __attribute__((ext_vector_type(4))) float f32x4;

__device__ __forceinline__ ushort f2bf(float f) {
    unsigned u = __float_as_uint(f);
    u += 0x7FFFu + ((u >> 16) & 1u);          // round-to-nearest-even
    return (ushort)(u >> 16);
}
__device__ __forceinline__ float bf2f(ushort h) {
    return __uint_as_float(((unsigned)h) << 16);
}
__device__ __forceinline__ __half2 u2h2(unsigned u) {
    union { unsigned u; __half2 h; } c; c.u = u; return c.h;
}
// ROCm 7.2 hip_fp16.h lacks __half2 overloads of these on this path; emit
// the packed ops directly (single VOP3P instrs).
__device__ __forceinline__ __half2 hmax2(__half2 a, __half2 b) {
    __half2 r;
    asm("v_pk_max_f16 %0, %1, %2" : "=v"(r) : "v"(a), "v"(b));
    return r;
}
__device__ __forceinline__ unsigned pkmul_u(unsigned a, __half2 s) {
    unsigned r;
    asm("v_pk_mul_f16 %0, %1, %2" : "=v"(r) : "v"(a), "v"(s));
    return r;
}

// ---------------------------------------------------------------------------
// x [B][C][HW] fp32 -> xt [B][HW][C] bf16 (pixel-major, K-contiguous)
// ---------------------------------------------------------------------------
__global__ __launch_bounds__(256)
void x_to_bf16t(const float* __restrict__ x, ushort* __restrict__ xt)
{
    __shared__ float tile[32][33];
    const int t = threadIdx.x;
    const int hw0 = blockIdx.x * 32, c0 = blockIdx.y * 32, b = blockIdx.z;

    const int r = t >> 3, cc = (t & 7) * 4;
    const float4 v = *(const float4*)(x + ((size_t)b * NC + c0 + r) * HW + hw0 + cc);
    tile[r][cc + 0] = v.x; tile[r][cc + 1] = v.y; tile[r][cc + 2] = v.z; tile[r][cc + 3] = v.w;
    __syncthreads();

    const int hwr = t >> 3, c4 = (t & 7) * 4;
    ushort4 o;
    o.x = f2bf(tile[c4 + 0][hwr]);
    o.y = f2bf(tile[c4 + 1][hwr]);
    o.z = f2bf(tile[c4 + 2][hwr]);
    o.w = f2bf(tile[c4 + 3][hwr]);
    *(ushort4*)(xt + ((size_t)b * HW + hw0 + hwr) * NC + c0 + c4) = o;
}

// ---------------------------------------------------------------------------
// fp32 -> bf16 elementwise (weights). n must be multiple of 1024.
// ---------------------------------------------------------------------------
__global__ __launch_bounds__(256)
void conv_bf16(const float* __restrict__ w, ushort* __restrict__ o)
{
    const int i = (blockIdx.x * 256 + threadIdx.x) * 4;
    const float4 v = *(const float4*)(w + i);
    ushort4 u;
    u.x = f2bf(v.x); u.y = f2bf(v.y); u.z = f2bf(v.z); u.w = f2bf(v.w);
    *(ushort4*)(o + i) = u;
}

// ---------------------------------------------------------------------------
// MFMA GEMM: acc[m][hw] = sum_c A[m][c] * Bt[pixel][c]   (A,Bt bf16)
// 128x128 tile, BK=64, 4 waves (2x2). global_load_lds w=16, XOR-swizzled LDS.
// EPI=0: write f16 PIXEL-MAJOR [pixel][Mtot] via LDS-transposed epilogue.
// EPI=1: write fp32 m-major [b][256][hw] + bias + residual.
// ---------------------------------------------------------------------------
__device__ __forceinline__ void stage_tile(const ushort* __restrict__ g, ushort* lds,
                                           int w, int lane)
{
    const int lr  = lane >> 3;                  // row within 8-row chunk
    const int swz = ((lane & 7) ^ lr) * 8;      // pre-swizzled k-chunk (ushort units)
    #pragma unroll
    for (int ii = 0; ii < 4; ++ii) {
        const int rowbase = w * 32 + ii * 8;
        const ushort* src = g + (size_t)(rowbase + lr) * NC + swz;
        __builtin_amdgcn_global_load_lds((const __attribute__((address_space(1))) void*)src,
                                         (__attribute__((address_space(3))) void*)(lds + rowbase * 64),
                                         16, 0, 0);
    }
}

template<int EPI>
__global__ __launch_bounds__(256)
void gemm_mfma(const ushort* __restrict__ A, const ushort* __restrict__ Bt,
               void* __restrict__ Cout, const float* __restrict__ bias,
               const float* __restrict__ res, int Mtot)
{
    __shared__ __align__(16) ushort smem[128 * 136];   // main: As|Bs; epi0: transpose
    ushort* As = smem;
    ushort* Bs = smem + 128 * 64;

    const int t = threadIdx.x;
    const int lane = t & 63, w = t >> 6;
    const int wm = w >> 1, wn = w & 1;
    const int n0 = blockIdx.x * 128;
    const int m0 = blockIdx.y * 128;

    const ushort* Ag = A + (size_t)m0 * NC;
    const ushort* Bg = Bt + (size_t)n0 * NC;

    f32x4 acc[4][4];
    #pragma unroll
    for (int i = 0; i < 4; ++i)
        #pragma unroll
        for (int j = 0; j < 4; ++j)
            acc[i][j] = (f32x4){0.f, 0.f, 0.f, 0.f};

    for (int k0 = 0; k0 < NC; k0 += 64) {
        stage_tile(Ag + k0, As, w, lane);
        stage_tile(Bg + k0, Bs, w, lane);
        __syncthreads();
        #pragma unroll
        for (int ks = 0; ks < 2; ++ks) {
            const int kc = (lane >> 4) + ks * 4;
            const int sw = (kc ^ (lane & 7)) * 8;
            short8v af[4], bf_[4];
            #pragma unroll
            for (int f = 0; f < 4; ++f) {
                af[f]  = *(const short8v*)(As + (wm * 64 + f * 16 + (lane & 15)) * 64 + sw);
                bf_[f] = *(const short8v*)(Bs + (wn * 64 + f * 16 + (lane & 15)) * 64 + sw);
            }
            #pragma unroll
            for (int fi = 0; fi < 4; ++fi)
                #pragma unroll
                for (int fj = 0; fj < 4; ++fj)
                    acc[fi][fj] = __builtin_amdgcn_mfma_f32_16x16x32_bf16(af[fi], bf_[fj], acc[fi][fj], 0, 0, 0);
        }
        __syncthreads();
    }

    const int b = n0 / HW;                       // 9216 % 128 == 0: no straddle
    const int hw0 = n0 - b * HW;

    if constexpr (EPI == 0) {
        // acc -> LDS [hw_local][m_local] (stride 136: 272B rows, 16B-aligned)
        #pragma unroll
        for (int fi = 0; fi < 4; ++fi)
            #pragma unroll
            for (int fj = 0; fj < 4; ++fj) {
                const int hwl = wn * 64 + fj * 16 + (lane & 15);
                const int ml  = wm * 64 + fi * 16 + (lane >> 4) * 4;
                ushort4 v4;
                v4.x = __half_as_ushort(__float2half_rn(acc[fi][fj][0]));
                v4.y = __half_as_ushort(__float2half_rn(acc[fi][fj][1]));
                v4.z = __half_as_ushort(__float2half_rn(acc[fi][fj][2]));
                v4.w = __half_as_ushort(__float2half_rn(acc[fi][fj][3]));
                *(ushort4*)(smem + hwl * 136 + ml) = v4;
            }
        __syncthreads();
        ushort* C = (ushort*)Cout;
        #pragma unroll
        for (int it = 0; it < 8; ++it) {
            const int cid = it * 256 + t;
            const int hwl = cid >> 4, mc = (cid & 15) * 8;
            const uint4 v = *(const uint4*)(smem + hwl * 136 + mc);
            *(uint4*)(C + ((size_t)b * HW + hw0 + hwl) * (size_t)Mtot + m0 + mc) = v;
        }
    } else {
        float* C = (float*)Cout;
        const int ncol = hw0 + wn * 64 + (lane & 15);
        #pragma unroll
        for (int fi = 0; fi < 4; ++fi)
            #pragma unroll
            for (int r = 0; r < 4; ++r) {
                const int m = m0 + wm * 64 + fi * 16 + (lane >> 4) * 4 + r;
                const float bm = bias[m];
                const size_t base = ((size_t)b * NC + m) * HW + ncol;
                #pragma unroll
                for (int fj = 0; fj < 4; ++fj)
                    C[base + fj * 16] = acc[fi][fj][r] + bm + res[base + fj * 16];
            }
    }
}

// ---------------------------------------------------------------------------
// Attention. qkvp: f16 pixel-major [b][hw][768] (q 0..255, k 256..511, v 512..767).
// Block = 32 center px (2 rows x 16 cols), one head, one batch. 512 threads.
// Thread owns 2 softmax rows (channels n0r, n0r+1) of one pixel (t&31).
// Halo = 4x18 = 72 px. vsum (3x3 box sum of v) computed in-LDS.
// ---------------------------------------------------------------------------
__global__ __launch_bounds__(512, 1)
void attn_px(const ushort* __restrict__ qkvp, ushort* __restrict__ att)
{
    __shared__ ushort qh[72 * 40];   // [halo px][32 ch] f16 (q pre-scaled)
    __shared__ ushort kh[72 * 40];
    __shared__ ushort vh[72 * 40];
    __shared__ ushort vs[32 * 40];   // [center px][32 m] f16 box-sum

    const int t = threadIdx.x;
    const int sraw = blockIdx.x;                       // 0..287
    const int s = (sraw & 7) * 36 + (sraw >> 3);       // XCD-chunked (288=8*36)
    const int h = blockIdx.y;
    const int b = blockIdx.z;
    const int I0 = (s / 6) * 2;                        // center row pair
    const int j0 = (s - (s / 6) * 6) * 16;             // center col start

    const ushort* P = qkvp + (size_t)b * HW * 768;
    const int qo = h * HD, ko = NC + h * HD, vo = 2 * NC + h * HD;
    const __half2 sc2 = __float2half2_rn(SCALE);

    // ---- stage q/k/v halos: 72 px x 3 arrays x 4 chunks of 16B = 864 units ----
    #pragma unroll
    for (int pass = 0; pass < 2; ++pass) {
        const int u = t + pass * 512;
        if (u < 864) {
            const int arr = (u < 288) ? 0 : ((u < 576) ? 1 : 2);
            const int wi = u - arr * 288;
            const int hp = wi >> 2, c8 = (wi & 3) * 8;
            const int hy = hp / 18, hx = hp - hy * 18;
            const int gi = I0 - 1 + hy, gj = j0 - 1 + hx;
            uint4 v = {0, 0, 0, 0};
            const int off = (arr == 0) ? qo : ((arr == 1) ? ko : vo);
            if (gi >= 0 && gi < H96 && gj >= 0 && gj < W96)
                v = *(const uint4*)(P + ((size_t)gi * W96 + gj) * 768 + off + c8);
            if (arr == 0) {
                v.x = pkmul_u(v.x, sc2); v.y = pkmul_u(v.y, sc2);
                v.z = pkmul_u(v.z, sc2); v.w = pkmul_u(v.w, sc2);
                *(uint4*)(qh + hp * 40 + c8) = v;
            } else if (arr == 1) {
                *(uint4*)(kh + hp * 40 + c8) = v;
            } else {
                *(uint4*)(vh + hp * 40 + c8) = v;
            }
        }
    }
    __syncthreads();

    // ---- vsum: 32 px x 16 half2 units, one per thread ----
    {
        const int px = t >> 4, m2 = (t & 15) * 2;
        const int r = px >> 4, c = px & 15;
        __half2 sv = __float2half2_rn(0.f);
        #pragma unroll
        for (int dy = 0; dy < 3; ++dy)
            #pragma unroll
            for (int dx = 0; dx < 3; ++dx)
                sv = __hadd2(sv, *(const __half2*)(vh + ((r + dy) * 18 + c + dx) * 40 + m2));
        *(__half2*)(vs + px * 40 + m2) = sv;
    }

    // ---- per-thread q fragments ----
    const int px = t & 31;
    const int r = px >> 4, c = px & 15;
    const int n0r = (t >> 5) * 2;

    __half2 q0[9], q1[9];
    int sidx[9];
    #pragma unroll
    for (int r9 = 0; r9 < 9; ++r9) {
        const int dy = r9 / 3, dj = r9 - dy * 3;
        const int si = (r + dy) * 18 + c + dj;
        sidx[r9] = si;
        const __half2 qq = *(const __half2*)(qh + si * 40 + n0r);   // [n0r, n0r+1]
        q0[r9] = __halves2half2(__low2half(qq), __low2half(qq));
        q1[r9] = __halves2half2(__high2half(qq), __high2half(qq));
    }

    // ---- dots ----
    __half2 d0[16], d1[16];
    const __half2 z2 = __float2half2_rn(0.f);
    #pragma unroll
    for (int j = 0; j < 16; ++j) { d0[j] = z2; d1[j] = z2; }

    #pragma unroll
    for (int r9 = 0; r9 < 9; ++r9) {
        const uint4* kp = (const uint4*)(kh + sidx[r9] * 40);
        #pragma unroll
        for (int mb = 0; mb < 4; ++mb) {
            const uint4 kq = kp[mb];
            const __half2 k0 = u2h2(kq.x), k1 = u2h2(kq.y), k2 = u2h2(kq.z), k3 = u2h2(kq.w);
            d0[mb * 4 + 0] = __hfma2(q0[r9], k0, d0[mb * 4 + 0]);
            d0[mb * 4 + 1] = __hfma2(q0[r9], k1, d0[mb * 4 + 1]);
            d0[mb * 4 + 2] = __hfma2(q0[r9], k2, d0[mb * 4 + 2]);
            d0[mb * 4 + 3] = __hfma2(q0[r9], k3, d0[mb * 4 + 3]);
            d1[mb * 4 + 0] = __hfma2(q1[r9], k0, d1[mb * 4 + 0]);
            d1[mb * 4 + 1] = __hfma2(q1[r9], k1, d1[mb * 4 + 1]);
            d1[mb * 4 + 2] = __hfma2(q1[r9], k2, d1[mb * 4 + 2]);
            d1[mb * 4 + 3] = __hfma2(q1[r9], k3, d1[mb * 4 + 3]);
        }
    }
    __syncthreads();   // vs visible before PV

    // ---- softmax over m (fully thread-local) ----
    __half2 m0 = d0[0], m1 = d1[0];
    #pragma unroll
    for (int j = 1; j < 16; ++j) { m0 = hmax2(m0, d0[j]); m1 = hmax2(m1, d1[j]); }
    const __half2 mx0 = __float2half2_rn(fmaxf(__low2float(m0), __high2float(m0)));
    const __half2 mx1 = __float2half2_rn(fmaxf(__low2float(m1), __high2float(m1)));

    __half2 s0 = z2, s1 = z2;
    #pragma unroll
    for (int j = 0; j < 16; ++j) {
        d0[j] = h2exp(__hsub2(d0[j], mx0)); s0 = __hadd2(s0, d0[j]);
        d1[j] = h2exp(__hsub2(d1[j], mx1)); s1 = __hadd2(s1, d1[j]);
    }
    const float den0 = __low2float(s0) + __high2float(s0);
    const float den1 = __low2float(s1) + __high2float(s1);

    // ---- PV with vsum ----
    __half2 o0 = z2, o1 = z2;
    const uint4* vp = (const uint4*)(vs + px * 40);
    #pragma unroll
    for (int mb = 0; mb < 4; ++mb) {
        const uint4 vq = vp[mb];
        const __half2 v0 = u2h2(vq.x), v1 = u2h2(vq.y), v2 = u2h2(vq.z), v3 = u2h2(vq.w);
        o0 = __hfma2(d0[mb * 4 + 0], v0, o0); o0 = __hfma2(d0[mb * 4 + 1], v1, o0);
        o0 = __hfma2(d0[mb * 4 + 2], v2, o0); o0 = __hfma2(d0[mb * 4 + 3], v3, o0);
        o1 = __hfma2(d1[mb * 4 + 0], v0, o1); o1 = __hfma2(d1[mb * 4 + 1], v1, o1);
        o1 = __hfma2(d1[mb * 4 + 2], v2, o1); o1 = __hfma2(d1[mb * 4 + 3], v3, o1);
    }
    const float fo0 = (__low2float(o0) + __high2float(o0)) / den0;
    const float fo1 = (__low2float(o1) + __high2float(o1)) / den1;

    // ---- direct pixel-major bf16 store (block fully covers its 64B lines) ----
    ushort2 uo; uo.x = f2bf(fo0); uo.y = f2bf(fo1);
    *(ushort2*)(att + ((size_t)b * HW + (size_t)(I0 + r) * W96 + j0 + c) * NC + h * HD + n0r) = uo;
}

// ---------------------------------------------------------------------------
extern "C" void kernel_launch(void* const* d_in, const int* in_sizes, int n_in,
                              void* d_out, int out_size, void* d_ws, size_t ws_size,
                              hipStream_t stream)
{
    (void)in_sizes; (void)n_in; (void)out_size; (void)ws_size;
    const float* x     = (const float*)d_in[0];
    const float* w_qkv = (const float*)d_in[1];
    const float* w_out = (const float*)d_in[2];
    const float* b_out = (const float*)d_in[3];
    float* out = (float*)d_out;

    ushort* qkvp = (ushort*)d_ws;                        // [B*HW][768] f16  28.3 MB
    ushort* attb = qkvp + (size_t)NB * HW * 768;         // [B*HW][256] bf16  9.4 MB
    ushort* xt   = attb + (size_t)NB * HW * NC;          // [B*HW][256] bf16  9.4 MB
    ushort* wqb  = xt   + (size_t)NB * HW * NC;          // [768][256] bf16
    ushort* wob  = wqb  + 768 * NC;                      // [256][256] bf16

    x_to_bf16t<<<dim3(HW / 32, NC / 32, NB), 256, 0, stream>>>(x, xt);
    conv_bf16<<<dim3(768 * NC / 1024), 256, 0, stream>>>(w_qkv, wqb);
    conv_bf16<<<dim3(NC * NC / 1024), 256, 0, stream>>>(w_out, wob);
    // qkv = w_qkv @ x -> f16 pixel-major
    gemm_mfma<0><<<dim3(144, 6), 256, 0, stream>>>(wqb, xt, qkvp, nullptr, nullptr, 768);
    // local attention (fused box-sum) -> bf16 pixel-major
    attn_px<<<dim3(288, NHEADS, NB), 512, 0, stream>>>(qkvp, attb);
    // out = w_out @ att + b_out + x (fp32 m-major)
    gemm_mfma<1><<<dim3(144, 2), 256, 0, stream>>>(wob, attb, out, b_out, x, 256);
}

// Round 7
// 161.584 us; speedup vs baseline: 2.0273x; 1.0630x over previous
//
#include <hip/hip_runtime.h>

#define H96 96
#define W96 96
#define HW  9216          // 96*96
#define NC  256
#define NB  2
#define NHEADS 8
#define HD  32
#define SCALE 0.17677669529663687f   // 1/sqrt(32)

typedef __attribute__((ext_vector_type(8))) short short8v;    // 8 bf16 (4 VGPRs)
typedef __attribute__((ext_vector_type(4))) float f32x4;
typedef __attribute__((ext_vector_type(16))) float f32x16;

__device__ __forceinline__ ushort f2bf(float f) {
    unsigned u = __float_as_uint(f);
    u += 0x7FFFu + ((u >> 16) & 1u);          // round-to-nearest-even
    return (ushort)(u >> 16);
}
__device__ __forceinline__ float bf2f(ushort h) {
    return __uint_as_float(((unsigned)h) << 16);
}

// ---------------------------------------------------------------------------
// x [B][C][HW] fp32 -> xt [B][HW][C] bf16 (pixel-major, K-contiguous)
// ---------------------------------------------------------------------------
__global__ __launch_bounds__(256)
void x_to_bf16t(const float* __restrict__ x, ushort* __restrict__ xt)
{
    __shared__ float tile[32][33];
    const int t = threadIdx.x;
    const int hw0 = blockIdx.x * 32, c0 = blockIdx.y * 32, b = blockIdx.z;

    const int r = t >> 3, cc = (t & 7) * 4;
    const float4 v = *(const float4*)(x + ((size_t)b * NC + c0 + r) * HW + hw0 + cc);
    tile[r][cc + 0] = v.x; tile[r][cc + 1] = v.y; tile[r][cc + 2] = v.z; tile[r][cc + 3] = v.w;
    __syncthreads();

    const int hwr = t >> 3, c4 = (t & 7) * 4;
    ushort4 o;
    o.x = f2bf(tile[c4 + 0][hwr]);
    o.y = f2bf(tile[c4 + 1][hwr]);
    o.z = f2bf(tile[c4 + 2][hwr]);
    o.w = f2bf(tile[c4 + 3][hwr]);
    *(ushort4*)(xt + ((size_t)b * HW + hw0 + hwr) * NC + c0 + c4) = o;
}

// ---------------------------------------------------------------------------
// fp32 -> bf16 elementwise (weights). n must be multiple of 1024.
// ---------------------------------------------------------------------------
__global__ __launch_bounds__(256)
void conv_bf16(const float* __restrict__ w, ushort* __restrict__ o)
{
    const int i = (blockIdx.x * 256 + threadIdx.x) * 4;
    const float4 v = *(const float4*)(w + i);
    ushort4 u;
    u.x = f2bf(v.x); u.y = f2bf(v.y); u.z = f2bf(v.z); u.w = f2bf(v.w);
    *(ushort4*)(o + i) = u;
}

// ---------------------------------------------------------------------------
// MFMA GEMM: acc[m][hw] = sum_c A[m][c] * Bt[pixel][c]   (A,Bt bf16)
// 128x128 tile, BK=64, 4 waves (2x2). global_load_lds w=16, XOR-swizzled LDS.
// EPI=0: write bf16 PIXEL-MAJOR [pixel][Mtot] via LDS-transposed epilogue.
// EPI=1: write fp32 m-major [b][256][hw] + bias + residual.
// ---------------------------------------------------------------------------
__device__ __forceinline__ void stage_tile(const ushort* __restrict__ g, ushort* lds,
                                           int w, int lane)
{
    const int lr  = lane >> 3;                  // row within 8-row chunk
    const int swz = ((lane & 7) ^ lr) * 8;      // pre-swizzled k-chunk (ushort units)
    #pragma unroll
    for (int ii = 0; ii < 4; ++ii) {
        const int rowbase = w * 32 + ii * 8;
        const ushort* src = g + (size_t)(rowbase + lr) * NC + swz;
        __builtin_amdgcn_global_load_lds((const __attribute__((address_space(1))) void*)src,
                                         (__attribute__((address_space(3))) void*)(lds + rowbase * 64),
                                         16, 0, 0);
    }
}

template<int EPI>
__global__ __launch_bounds__(256)
void gemm_mfma(const ushort* __restrict__ A, const ushort* __restrict__ Bt,
               void* __restrict__ Cout, const float* __restrict__ bias,
               const float* __restrict__ res, int Mtot)
{
    __shared__ __align__(16) ushort smem[128 * 136];   // main: As|Bs; epi0: transpose
    ushort* As = smem;
    ushort* Bs = smem + 128 * 64;

    const int t = threadIdx.x;
    const int lane = t & 63, w = t >> 6;
    const int wm = w >> 1, wn = w & 1;
    const int n0 = blockIdx.x * 128;
    const int m0 = blockIdx.y * 128;

    const ushort* Ag = A + (size_t)m0 * NC;
    const ushort* Bg = Bt + (size_t)n0 * NC;

    f32x4 acc[4][4];
    #pragma unroll
    for (int i = 0; i < 4; ++i)
        #pragma unroll
        for (int j = 0; j < 4; ++j)
            acc[i][j] = (f32x4){0.f, 0.f, 0.f, 0.f};

    for (int k0 = 0; k0 < NC; k0 += 64) {
        stage_tile(Ag + k0, As, w, lane);
        stage_tile(Bg + k0, Bs, w, lane);
        __syncthreads();
        #pragma unroll
        for (int ks = 0; ks < 2; ++ks) {
            const int kc = (lane >> 4) + ks * 4;
            const int sw = (kc ^ (lane & 7)) * 8;
            short8v af[4], bf_[4];
            #pragma unroll
            for (int f = 0; f < 4; ++f) {
                af[f]  = *(const short8v*)(As + (wm * 64 + f * 16 + (lane & 15)) * 64 + sw);
                bf_[f] = *(const short8v*)(Bs + (wn * 64 + f * 16 + (lane & 15)) * 64 + sw);
            }
            #pragma unroll
            for (int fi = 0; fi < 4; ++fi)
                #pragma unroll
                for (int fj = 0; fj < 4; ++fj)
                    acc[fi][fj] = __builtin_amdgcn_mfma_f32_16x16x32_bf16(af[fi], bf_[fj], acc[fi][fj], 0, 0, 0);
        }
        __syncthreads();
    }

    const int b = n0 / HW;                       // 9216 % 128 == 0: no straddle
    const int hw0 = n0 - b * HW;

    if constexpr (EPI == 0) {
        // acc -> LDS [hw_local][m_local] (stride 136: 272B rows, 16B-aligned)
        #pragma unroll
        for (int fi = 0; fi < 4; ++fi)
            #pragma unroll
            for (int fj = 0; fj < 4; ++fj) {
                const int hwl = wn * 64 + fj * 16 + (lane & 15);
                const int ml  = wm * 64 + fi * 16 + (lane >> 4) * 4;
                ushort4 v4;
                v4.x = f2bf(acc[fi][fj][0]);
                v4.y = f2bf(acc[fi][fj][1]);
                v4.z = f2bf(acc[fi][fj][2]);
                v4.w = f2bf(acc[fi][fj][3]);
                *(ushort4*)(smem + hwl * 136 + ml) = v4;
            }
        __syncthreads();
        ushort* C = (ushort*)Cout;
        #pragma unroll
        for (int it = 0; it < 8; ++it) {
            const int cid = it * 256 + t;
            const int hwl = cid >> 4, mc = (cid & 15) * 8;
            const uint4 v = *(const uint4*)(smem + hwl * 136 + mc);
            *(uint4*)(C + ((size_t)b * HW + hw0 + hwl) * (size_t)Mtot + m0 + mc) = v;
        }
    } else {
        float* C = (float*)Cout;
        const int ncol = hw0 + wn * 64 + (lane & 15);
        #pragma unroll
        for (int fi = 0; fi < 4; ++fi)
            #pragma unroll
            for (int r = 0; r < 4; ++r) {
                const int m = m0 + wm * 64 + fi * 16 + (lane >> 4) * 4 + r;
                const float bm = bias[m];
                const size_t base = ((size_t)b * NC + m) * HW + ncol;
                #pragma unroll
                for (int fj = 0; fj < 4; ++fj)
                    C[base + fj * 16] = acc[fi][fj][r] + bm + res[base + fj * 16];
            }
    }
}

// ---------------------------------------------------------------------------
// Attention via MFMA. qkvp: bf16 pixel-major [b][hw][768].
// Block = 16-px strip (1 row), one head, one batch. 256 threads = 4 waves.
// Each wave computes 4 pixels, one v_mfma_f32_32x32x16_bf16 per pixel:
//   dots[m][n] = sum_s k[m@s] * q[n@s]   (s = 9 window slots in k-dim, padded)
// A-frag (k): lane holds row m=lane&31, k-slots (lane>>5)*8+e; invalid slots
// zeroed on A side only (0*x=0). B-frag (q): col n=lane&31, same k mapping.
// C: col n = lane&31, rows m = (reg&3)+8*(reg>>2)+4*(lane>>5)  [m101].
// Softmax over m: 15 reg-max + shfl_xor(32); exp f32; PV vs f32 vsum; combine.
// ---------------------------------------------------------------------------
__global__ __launch_bounds__(256)
void attn_mfma(const ushort* __restrict__ qkvp, ushort* __restrict__ att)
{
    __shared__ ushort qh[54 * 40];   // [halo px][32 ch] bf16
    __shared__ ushort kh[54 * 40];
    __shared__ ushort vh[54 * 40];
    __shared__ float  vs[16 * 32];   // [center px][32 m] f32 box-sum

    const int t = threadIdx.x;
    const int sraw = blockIdx.x;                       // 0..575
    const int strip = (sraw & 7) * 72 + (sraw >> 3);   // XCD-chunked (bijective)
    const int h = blockIdx.y;
    const int b = blockIdx.z;
    const int i0 = strip / 6;
    const int j0 = (strip - (strip / 6) * 6) * 16;

    const ushort* P = qkvp + (size_t)b * HW * 768;
    const int qo = h * HD, ko = NC + h * HD, vo = 2 * NC + h * HD;

    // ---- stage q/k/v halos: 54 px x 4 chunks of 16B each ----
    if (t < 216) {
        const int px = t >> 2, c8 = (t & 3) * 8;
        const int dy = px / 18, dx = px - dy * 18;
        const int gi = i0 - 1 + dy, gj = j0 - 1 + dx;
        uint4 qv = {0, 0, 0, 0}, kv = {0, 0, 0, 0}, vv = {0, 0, 0, 0};
        if (gi >= 0 && gi < H96 && gj >= 0 && gj < W96) {
            const ushort* pp = P + ((size_t)gi * W96 + gj) * 768;
            qv = *(const uint4*)(pp + qo + c8);
            kv = *(const uint4*)(pp + ko + c8);
            vv = *(const uint4*)(pp + vo + c8);
        }
        *(uint4*)(qh + px * 40 + c8) = qv;
        *(uint4*)(kh + px * 40 + c8) = kv;
        *(uint4*)(vh + px * 40 + c8) = vv;
    }
    __syncthreads();

    // ---- vsum (3x3 box sum of v) in f32: 16 px x 16 channel-pairs ----
    {
        const int px = t >> 4, m2 = (t & 15) * 2;
        float a0 = 0.f, a1 = 0.f;
        #pragma unroll
        for (int dy = 0; dy < 3; ++dy)
            #pragma unroll
            for (int dx = 0; dx < 3; ++dx) {
                const ushort* pv = vh + (dy * 18 + px + dx) * 40 + m2;
                a0 += bf2f(pv[0]);
                a1 += bf2f(pv[1]);
            }
        vs[px * 32 + m2]     = a0;
        vs[px * 32 + m2 + 1] = a1;
    }
    __syncthreads();

    const int lane = t & 63, w = t >> 6;
    const int hi = lane >> 5, ch = lane & 31;

    #pragma unroll
    for (int p = 0; p < 4; ++p) {
        const int c = w * 4 + p;                 // center pixel column 0..15

        // ---- build fragments from LDS (16 ds_read_u16, 64B/instr, no conflict)
        short8v ak, bq;
        #pragma unroll
        for (int e = 0; e < 8; ++e) {
            // window slot s = hi*8+e; delta(s) = (s/3)*18 + s%3 for s<9
            const int DLO[8] = {0, 1, 2, 18, 19, 20, 36, 37};
            const int d = hi ? (e == 0 ? 38 : 0) : DLO[e];
            ushort kv = kh[(d + c) * 40 + ch];
            const ushort qv = qh[(d + c) * 40 + ch];
            if (hi && e > 0) kv = 0;             // zero invalid k-slots (A side)
            ak[e] = (short)kv;
            bq[e] = (short)qv;
        }

        f32x16 dm;
        #pragma unroll
        for (int r = 0; r < 16; ++r) dm[r] = 0.f;
        dm = __builtin_amdgcn_mfma_f32_32x32x16_bf16(ak, bq, dm, 0, 0, 0);

        // ---- softmax over m (rows): 16 local + the other half via shfl ----
        float mx = dm[0];
        #pragma unroll
        for (int r = 1; r < 16; ++r) mx = fmaxf(mx, dm[r]);
        mx = fmaxf(mx, __shfl_xor(mx, 32));
        const float msx = mx * SCALE;

        float vsv[16];
        #pragma unroll
        for (int g = 0; g < 4; ++g) {
            const float4 vv = *(const float4*)(vs + c * 32 + g * 8 + hi * 4);
            vsv[g * 4 + 0] = vv.x; vsv[g * 4 + 1] = vv.y;
            vsv[g * 4 + 2] = vv.z; vsv[g * 4 + 3] = vv.w;
        }

        float sum = 0.f, out = 0.f;
        #pragma unroll
        for (int r = 0; r < 16; ++r) {
            const float pe = __expf(fmaf(dm[r], SCALE, -msx));
            sum += pe;
            out = fmaf(pe, vsv[r], out);
        }
        sum += __shfl_xor(sum, 32);
        out += __shfl_xor(out, 32);

        if (hi == 0) {
            att[((size_t)b * HW + (size_t)i0 * W96 + j0 + c) * NC + h * HD + ch] =
                f2bf(out / sum);
        }
    }
}

// ---------------------------------------------------------------------------
extern "C" void kernel_launch(void* const* d_in, const int* in_sizes, int n_in,
                              void* d_out, int out_size, void* d_ws, size_t ws_size,
                              hipStream_t stream)
{
    (void)in_sizes; (void)n_in; (void)out_size; (void)ws_size;
    const float* x     = (const float*)d_in[0];
    const float* w_qkv = (const float*)d_in[1];
    const float* w_out = (const float*)d_in[2];
    const float* b_out = (const float*)d_in[3];
    float* out = (float*)d_out;

    ushort* qkvp = (ushort*)d_ws;                        // [B*HW][768] bf16 28.3 MB
    ushort* attb = qkvp + (size_t)NB * HW * 768;         // [B*HW][256] bf16  9.4 MB
    ushort* xt   = attb + (size_t)NB * HW * NC;          // [B*HW][256] bf16  9.4 MB
    ushort* wqb  = xt   + (size_t)NB * HW * NC;          // [768][256] bf16
    ushort* wob  = wqb  + 768 * NC;                      // [256][256] bf16

    x_to_bf16t<<<dim3(HW / 32, NC / 32, NB), 256, 0, stream>>>(x, xt);
    conv_bf16<<<dim3(768 * NC / 1024), 256, 0, stream>>>(w_qkv, wqb);
    conv_bf16<<<dim3(NC * NC / 1024), 256, 0, stream>>>(w_out, wob);
    // qkv = w_qkv @ x -> bf16 pixel-major
    gemm_mfma<0><<<dim3(144, 6), 256, 0, stream>>>(wqb, xt, qkvp, nullptr, nullptr, 768);
    // local attention: MFMA dots + fused box-sum -> bf16 pixel-major
    attn_mfma<<<dim3(576, NHEADS, NB), 256, 0, stream>>>(qkvp, attb);
    // out = w_out @ att + b_out + x (fp32 m-major)
    gemm_mfma<1><<<dim3(144, 2), 256, 0, stream>>>(wob, attb, out, b_out, x, 256);
}

// Round 8
// 161.075 us; speedup vs baseline: 2.0337x; 1.0032x over previous
//
#include <hip/hip_runtime.h>

#define H96 96
#define W96 96
#define HW  9216          // 96*96
#define NC  256
#define NB  2
#define NHEADS 8
#define HD  32
#define SCALE 0.17677669529663687f   // 1/sqrt(32)

typedef __attribute__((ext_vector_type(8))) short short8v;    // 8 bf16 (4 VGPRs)
typedef __attribute__((ext_vector_type(4))) float f32x4;
typedef __attribute__((ext_vector_type(16))) float f32x16;

__device__ __forceinline__ ushort f2bf(float f) {
    unsigned u = __float_as_uint(f);
    u += 0x7FFFu + ((u >> 16) & 1u);          // round-to-nearest-even
    return (ushort)(u >> 16);
}
__device__ __forceinline__ float bf2f(ushort h) {
    return __uint_as_float(((unsigned)h) << 16);
}

// ---------------------------------------------------------------------------
// x [B][C][HW] fp32 -> xt [B][HW][C] bf16 (pixel-major) AND xbm (m-major bf16)
// ---------------------------------------------------------------------------
__global__ __launch_bounds__(256)
void x_to_bf16t(const float* __restrict__ x, ushort* __restrict__ xt,
                ushort* __restrict__ xbm)
{
    __shared__ float tile[32][33];
    const int t = threadIdx.x;
    const int hw0 = blockIdx.x * 32, c0 = blockIdx.y * 32, b = blockIdx.z;

    const int r = t >> 3, cc = (t & 7) * 4;
    const size_t gidx = ((size_t)b * NC + c0 + r) * HW + hw0 + cc;
    const float4 v = *(const float4*)(x + gidx);
    tile[r][cc + 0] = v.x; tile[r][cc + 1] = v.y; tile[r][cc + 2] = v.z; tile[r][cc + 3] = v.w;
    // m-major bf16 copy for gemm2 residual (coalesced, same addresses)
    ushort4 ob;
    ob.x = f2bf(v.x); ob.y = f2bf(v.y); ob.z = f2bf(v.z); ob.w = f2bf(v.w);
    *(ushort4*)(xbm + gidx) = ob;
    __syncthreads();

    const int hwr = t >> 3, c4 = (t & 7) * 4;
    ushort4 o;
    o.x = f2bf(tile[c4 + 0][hwr]);
    o.y = f2bf(tile[c4 + 1][hwr]);
    o.z = f2bf(tile[c4 + 2][hwr]);
    o.w = f2bf(tile[c4 + 3][hwr]);
    *(ushort4*)(xt + ((size_t)b * HW + hw0 + hwr) * NC + c0 + c4) = o;
}

// ---------------------------------------------------------------------------
// fp32 -> bf16 elementwise; first nscale elements multiplied by SCALE.
// ---------------------------------------------------------------------------
__global__ __launch_bounds__(256)
void conv_bf16(const float* __restrict__ w, ushort* __restrict__ o, int nscale)
{
    const int i = (blockIdx.x * 256 + threadIdx.x) * 4;
    const float s = (i < nscale) ? SCALE : 1.0f;
    const float4 v = *(const float4*)(w + i);
    ushort4 u;
    u.x = f2bf(v.x * s); u.y = f2bf(v.y * s); u.z = f2bf(v.z * s); u.w = f2bf(v.w * s);
    *(ushort4*)(o + i) = u;
}

// ---------------------------------------------------------------------------
// MFMA GEMM: acc[m][hw] = sum_c A[m][c] * Bt[pixel][c]   (A,Bt bf16)
// 128x128 tile, BK=64, 4 waves (2x2). global_load_lds w=16, XOR-swizzled LDS.
// EPI=0: write bf16 PIXEL-MAJOR [pixel][Mtot] via LDS-transposed epilogue.
// EPI=1: write fp32 m-major [b][256][hw] + bias + bf16 residual.
// ---------------------------------------------------------------------------
__device__ __forceinline__ void stage_tile(const ushort* __restrict__ g, ushort* lds,
                                           int w, int lane)
{
    const int lr  = lane >> 3;                  // row within 8-row chunk
    const int swz = ((lane & 7) ^ lr) * 8;      // pre-swizzled k-chunk (ushort units)
    #pragma unroll
    for (int ii = 0; ii < 4; ++ii) {
        const int rowbase = w * 32 + ii * 8;
        const ushort* src = g + (size_t)(rowbase + lr) * NC + swz;
        __builtin_amdgcn_global_load_lds((const __attribute__((address_space(1))) void*)src,
                                         (__attribute__((address_space(3))) void*)(lds + rowbase * 64),
                                         16, 0, 0);
    }
}

template<int EPI>
__global__ __launch_bounds__(256)
void gemm_mfma(const ushort* __restrict__ A, const ushort* __restrict__ Bt,
               void* __restrict__ Cout, const float* __restrict__ bias,
               const ushort* __restrict__ resb, int Mtot)
{
    __shared__ __align__(16) ushort smem[128 * 136];   // main: As|Bs; epi0: transpose
    ushort* As = smem;
    ushort* Bs = smem + 128 * 64;

    const int t = threadIdx.x;
    const int lane = t & 63, w = t >> 6;
    const int wm = w >> 1, wn = w & 1;
    const int n0 = blockIdx.x * 128;
    const int m0 = blockIdx.y * 128;

    const ushort* Ag = A + (size_t)m0 * NC;
    const ushort* Bg = Bt + (size_t)n0 * NC;

    f32x4 acc[4][4];
    #pragma unroll
    for (int i = 0; i < 4; ++i)
        #pragma unroll
        for (int j = 0; j < 4; ++j)
            acc[i][j] = (f32x4){0.f, 0.f, 0.f, 0.f};

    for (int k0 = 0; k0 < NC; k0 += 64) {
        stage_tile(Ag + k0, As, w, lane);
        stage_tile(Bg + k0, Bs, w, lane);
        __syncthreads();
        #pragma unroll
        for (int ks = 0; ks < 2; ++ks) {
            const int kc = (lane >> 4) + ks * 4;
            const int sw = (kc ^ (lane & 7)) * 8;
            short8v af[4], bf_[4];
            #pragma unroll
            for (int f = 0; f < 4; ++f) {
                af[f]  = *(const short8v*)(As + (wm * 64 + f * 16 + (lane & 15)) * 64 + sw);
                bf_[f] = *(const short8v*)(Bs + (wn * 64 + f * 16 + (lane & 15)) * 64 + sw);
            }
            #pragma unroll
            for (int fi = 0; fi < 4; ++fi)
                #pragma unroll
                for (int fj = 0; fj < 4; ++fj)
                    acc[fi][fj] = __builtin_amdgcn_mfma_f32_16x16x32_bf16(af[fi], bf_[fj], acc[fi][fj], 0, 0, 0);
        }
        __syncthreads();
    }

    const int b = n0 / HW;                       // 9216 % 128 == 0: no straddle
    const int hw0 = n0 - b * HW;

    if constexpr (EPI == 0) {
        // acc -> LDS [hw_local][m_local] (stride 136: 272B rows, 16B-aligned)
        #pragma unroll
        for (int fi = 0; fi < 4; ++fi)
            #pragma unroll
            for (int fj = 0; fj < 4; ++fj) {
                const int hwl = wn * 64 + fj * 16 + (lane & 15);
                const int ml  = wm * 64 + fi * 16 + (lane >> 4) * 4;
                ushort4 v4;
                v4.x = f2bf(acc[fi][fj][0]);
                v4.y = f2bf(acc[fi][fj][1]);
                v4.z = f2bf(acc[fi][fj][2]);
                v4.w = f2bf(acc[fi][fj][3]);
                *(ushort4*)(smem + hwl * 136 + ml) = v4;
            }
        __syncthreads();
        ushort* C = (ushort*)Cout;
        #pragma unroll
        for (int it = 0; it < 8; ++it) {
            const int cid = it * 256 + t;
            const int hwl = cid >> 4, mc = (cid & 15) * 8;
            const uint4 v = *(const uint4*)(smem + hwl * 136 + mc);
            *(uint4*)(C + ((size_t)b * HW + hw0 + hwl) * (size_t)Mtot + m0 + mc) = v;
        }
    } else {
        float* C = (float*)Cout;
        const int ncol = hw0 + wn * 64 + (lane & 15);
        #pragma unroll
        for (int fi = 0; fi < 4; ++fi)
            #pragma unroll
            for (int r = 0; r < 4; ++r) {
                const int m = m0 + wm * 64 + fi * 16 + (lane >> 4) * 4 + r;
                const float bm = bias[m];
                const size_t base = ((size_t)b * NC + m) * HW + ncol;
                #pragma unroll
                for (int fj = 0; fj < 4; ++fj)
                    C[base + fj * 16] = acc[fi][fj][r] + bm + bf2f(resb[base + fj * 16]);
            }
    }
}

// ---------------------------------------------------------------------------
// Attention via MFMA. qkvp: bf16 pixel-major [b][hw][768] (q pre-scaled).
// Block = 16-px strip, one head, one batch. 256 threads = 4 waves, 4 px/wave.
// One v_mfma_f32_32x32x16_bf16 per pixel: dots[m][n] = sum_s k[m@s]*q[n@s].
// Fragment reads: row = hi*36 + c + D[e] with zero-padded LDS rows so every
// read is ds_read_u16 with an immediate offset — no per-element selects.
//   DK = {0,1,2,18,19,20,54,55}: lo -> rows c+{0,1,2,18,19,20, Z,Z}
//                                hi -> rows c+{36,37,38, Z,Z,Z} (54..56, 90,91)
//   DQ = {0,1,2,18,19,20,0,0}: invalid q slots read real rows (ak=0 kills them)
// kh: 107 rows (zero 54..71 & 90..106); qh: 72 rows (zero 54..71).
// ---------------------------------------------------------------------------
__global__ __launch_bounds__(256)
void attn_mfma(const ushort* __restrict__ qkvp, ushort* __restrict__ att)
{
    __shared__ ushort kh[107 * 40];  // [row][32 ch] bf16 (+pad)
    __shared__ ushort qh[72 * 40];
    __shared__ ushort vh[54 * 40];
    __shared__ float  vs[16 * 32];   // [center px][32 m] f32 box-sum

    const int t = threadIdx.x;
    const int sraw = blockIdx.x;                       // 0..575
    const int strip = (sraw & 7) * 72 + (sraw >> 3);   // XCD-chunked (bijective)
    const int h = blockIdx.y;
    const int b = blockIdx.z;
    const int i0 = strip / 6;
    const int j0 = (strip - (strip / 6) * 6) * 16;

    const ushort* P = qkvp + (size_t)b * HW * 768;
    const int qo = h * HD, ko = NC + h * HD, vo = 2 * NC + h * HD;

    // ---- stage q/k/v halos: 54 px x 4 chunks of 16B each ----
    if (t < 216) {
        const int px = t >> 2, c8 = (t & 3) * 8;
        const int dy = px / 18, dx = px - dy * 18;
        const int gi = i0 - 1 + dy, gj = j0 - 1 + dx;
        uint4 qv = {0, 0, 0, 0}, kv = {0, 0, 0, 0}, vv = {0, 0, 0, 0};
        if (gi >= 0 && gi < H96 && gj >= 0 && gj < W96) {
            const ushort* pp = P + ((size_t)gi * W96 + gj) * 768;
            qv = *(const uint4*)(pp + qo + c8);
            kv = *(const uint4*)(pp + ko + c8);
            vv = *(const uint4*)(pp + vo + c8);
        }
        *(uint4*)(qh + px * 40 + c8) = qv;
        *(uint4*)(kh + px * 40 + c8) = kv;
        *(uint4*)(vh + px * 40 + c8) = vv;
    }
    // ---- zero pad rows: kh 54..71 & 90..106, qh 54..71 (53 rows x 5 uint4) ----
    {
        const int u = t;                       // 256 >= 265? no: loop twice
        #pragma unroll
        for (int pass = 0; pass < 2; ++pass) {
            const int z = u + pass * 256;
            if (z < 265) {
                const int row_id = z / 5, part = z - row_id * 5;
                ushort* dst;
                if (row_id < 18)      dst = kh + (54 + row_id) * 40;
                else if (row_id < 35) dst = kh + (90 + row_id - 18) * 40;
                else                  dst = qh + (54 + row_id - 35) * 40;
                *(uint4*)(dst + part * 8) = (uint4){0, 0, 0, 0};
            }
        }
    }
    __syncthreads();

    // ---- vsum (3x3 box sum of v) in f32: 16 px x 16 channel-pairs ----
    {
        const int px = t >> 4, m2 = (t & 15) * 2;
        float a0 = 0.f, a1 = 0.f;
        #pragma unroll
        for (int dy = 0; dy < 3; ++dy)
            #pragma unroll
            for (int dx = 0; dx < 3; ++dx) {
                const ushort* pv = vh + (dy * 18 + px + dx) * 40 + m2;
                a0 += bf2f(pv[0]);
                a1 += bf2f(pv[1]);
            }
        vs[px * 32 + m2]     = a0;
        vs[px * 32 + m2 + 1] = a1;
    }
    __syncthreads();

    const int lane = t & 63, w = t >> 6;
    const int hi = lane >> 5, ch = lane & 31;

    const ushort* kb = kh + (hi * 36 + w * 4) * 40 + ch;
    const ushort* qb = qh + (hi * 36 + w * 4) * 40 + ch;

    #pragma unroll
    for (int p = 0; p < 4; ++p) {
        const int c = w * 4 + p;                 // center pixel column 0..15

        short8v ak, bq;
        #pragma unroll
        for (int e = 0; e < 8; ++e) {
            const int DK[8] = {0, 1, 2, 18, 19, 20, 54, 55};
            const int DQ[8] = {0, 1, 2, 18, 19, 20, 0, 0};
            ak[e] = (short)kb[(p + DK[e]) * 40];
            bq[e] = (short)qb[(p + DQ[e]) * 40];
        }

        f32x16 dm;
        #pragma unroll
        for (int r = 0; r < 16; ++r) dm[r] = 0.f;
        dm = __builtin_amdgcn_mfma_f32_32x32x16_bf16(ak, bq, dm, 0, 0, 0);

        // ---- softmax over m (rows): 16 local + other half via shfl ----
        float mx = dm[0];
        #pragma unroll
        for (int r = 1; r < 16; ++r) mx = fmaxf(mx, dm[r]);
        mx = fmaxf(mx, __shfl_xor(mx, 32));

        float vsv[16];
        #pragma unroll
        for (int g = 0; g < 4; ++g) {
            const float4 vv = *(const float4*)(vs + c * 32 + g * 8 + hi * 4);
            vsv[g * 4 + 0] = vv.x; vsv[g * 4 + 1] = vv.y;
            vsv[g * 4 + 2] = vv.z; vsv[g * 4 + 3] = vv.w;
        }

        float sum = 0.f, out = 0.f;
        #pragma unroll
        for (int r = 0; r < 16; ++r) {
            const float pe = __expf(dm[r] - mx);     // dots pre-scaled via weights
            sum += pe;
            out = fmaf(pe, vsv[r], out);
        }
        sum += __shfl_xor(sum, 32);
        out += __shfl_xor(out, 32);

        if (hi == 0) {
            att[((size_t)b * HW + (size_t)i0 * W96 + j0 + c) * NC + h * HD + ch] =
                f2bf(out / sum);
        }
    }
}

// ---------------------------------------------------------------------------
extern "C" void kernel_launch(void* const* d_in, const int* in_sizes, int n_in,
                              void* d_out, int out_size, void* d_ws, size_t ws_size,
                              hipStream_t stream)
{
    (void)in_sizes; (void)n_in; (void)out_size; (void)ws_size;
    const float* x     = (const float*)d_in[0];
    const float* w_qkv = (const float*)d_in[1];
    const float* w_out = (const float*)d_in[2];
    const float* b_out = (const float*)d_in[3];
    float* out = (float*)d_out;

    ushort* qkvp = (ushort*)d_ws;                        // [B*HW][768] bf16 28.3 MB
    ushort* attb = qkvp + (size_t)NB * HW * 768;         // [B*HW][256] bf16  9.4 MB
    ushort* xt   = attb + (size_t)NB * HW * NC;          // [B*HW][256] bf16  9.4 MB
    ushort* wqb  = xt   + (size_t)NB * HW * NC;          // [768][256] bf16
    ushort* wob  = wqb  + 768 * NC;                      // [256][256] bf16
    ushort* xbm  = wob  + NC * NC;                       // [B][256][HW] bf16 9.4 MB

    x_to_bf16t<<<dim3(HW / 32, NC / 32, NB), 256, 0, stream>>>(x, xt, xbm);
    conv_bf16<<<dim3(768 * NC / 1024), 256, 0, stream>>>(w_qkv, wqb, NC * NC); // q rows pre-scaled
    conv_bf16<<<dim3(NC * NC / 1024), 256, 0, stream>>>(w_out, wob, 0);
    // qkv = w_qkv @ x -> bf16 pixel-major
    gemm_mfma<0><<<dim3(144, 6), 256, 0, stream>>>(wqb, xt, qkvp, nullptr, nullptr, 768);
    // local attention: MFMA dots + fused box-sum -> bf16 pixel-major
    attn_mfma<<<dim3(576, NHEADS, NB), 256, 0, stream>>>(qkvp, attb);
    // out = w_out @ att + b_out + x (fp32 m-major, bf16 residual)
    gemm_mfma<1><<<dim3(144, 2), 256, 0, stream>>>(wob, attb, out, b_out, xbm, 256);
}

// Round 9
// 140.831 us; speedup vs baseline: 2.3260x; 1.1437x over previous
//
#include <hip/hip_runtime.h>

#define H96 96
#define W96 96
#define HW  9216          // 96*96
#define NC  256
#define NB  2
#define NHEADS 8
#define HD  32
#define SCALE 0.17677669529663687f   // 1/sqrt(32)

typedef __attribute__((ext_vector_type(8))) short short8v;    // 8 bf16 (4 VGPRs)
typedef __attribute__((ext_vector_type(4))) float f32x4;
typedef __attribute__((ext_vector_type(16))) float f32x16;

__device__ __forceinline__ ushort f2bf(float f) {
    unsigned u = __float_as_uint(f);
    u += 0x7FFFu + ((u >> 16) & 1u);          // round-to-nearest-even
    return (ushort)(u >> 16);
}
__device__ __forceinline__ float bf2f(ushort h) {
    return __uint_as_float(((unsigned)h) << 16);
}

// ---------------------------------------------------------------------------
// x [B][C][HW] fp32 -> xt [B][HW][C] bf16 (pixel-major) AND xbm (m-major bf16)
// ---------------------------------------------------------------------------
__global__ __launch_bounds__(256)
void x_to_bf16t(const float* __restrict__ x, ushort* __restrict__ xt,
                ushort* __restrict__ xbm)
{
    __shared__ float tile[32][33];
    const int t = threadIdx.x;
    const int hw0 = blockIdx.x * 32, c0 = blockIdx.y * 32, b = blockIdx.z;

    const int r = t >> 3, cc = (t & 7) * 4;
    const size_t gidx = ((size_t)b * NC + c0 + r) * HW + hw0 + cc;
    const float4 v = *(const float4*)(x + gidx);
    tile[r][cc + 0] = v.x; tile[r][cc + 1] = v.y; tile[r][cc + 2] = v.z; tile[r][cc + 3] = v.w;
    ushort4 ob;
    ob.x = f2bf(v.x); ob.y = f2bf(v.y); ob.z = f2bf(v.z); ob.w = f2bf(v.w);
    *(ushort4*)(xbm + gidx) = ob;
    __syncthreads();

    const int hwr = t >> 3, c4 = (t & 7) * 4;
    ushort4 o;
    o.x = f2bf(tile[c4 + 0][hwr]);
    o.y = f2bf(tile[c4 + 1][hwr]);
    o.z = f2bf(tile[c4 + 2][hwr]);
    o.w = f2bf(tile[c4 + 3][hwr]);
    *(ushort4*)(xt + ((size_t)b * HW + hw0 + hwr) * NC + c0 + c4) = o;
}

// ---------------------------------------------------------------------------
// Both weight conversions in one launch. q rows (first 65536 of w_qkv) are
// pre-scaled by SCALE*log2(e) so attn's softmax runs in exp2 domain.
// ---------------------------------------------------------------------------
__global__ __launch_bounds__(256)
void conv_w(const float* __restrict__ wq, const float* __restrict__ wo,
            ushort* __restrict__ oq, ushort* __restrict__ oo)
{
    const int bid = blockIdx.x;
    if (bid < 192) {                                   // 768*256 / 1024
        const int i = (bid * 256 + threadIdx.x) * 4;
        const float s = (i < 65536) ? (SCALE * 1.4426950408889634f) : 1.0f;
        const float4 v = *(const float4*)(wq + i);
        ushort4 u;
        u.x = f2bf(v.x * s); u.y = f2bf(v.y * s); u.z = f2bf(v.z * s); u.w = f2bf(v.w * s);
        *(ushort4*)(oq + i) = u;
    } else {                                           // 256*256 / 1024
        const int i = ((bid - 192) * 256 + threadIdx.x) * 4;
        const float4 v = *(const float4*)(wo + i);
        ushort4 u;
        u.x = f2bf(v.x); u.y = f2bf(v.y); u.z = f2bf(v.z); u.w = f2bf(v.w);
        *(ushort4*)(oo + i) = u;
    }
}

// ---------------------------------------------------------------------------
// MFMA GEMM: acc[m][hw] = sum_c A[m][c] * Bt[pixel][c]   (A,Bt bf16)
// 128x128 tile, BK=64, 4 waves (2x2). global_load_lds w=16, XOR-swizzled LDS.
// 1-D grid, XCD-chunked, m-tile fastest -> B-panel stays in the XCD's L2.
// EPI=0: bf16 pixel-major out (LDS-transposed epilogue). EPI=1: fp32 + bias
// + bf16 residual, m-major.
// ---------------------------------------------------------------------------
__device__ __forceinline__ void stage_tile(const ushort* __restrict__ g, ushort* lds,
                                           int w, int lane)
{
    const int lr  = lane >> 3;
    const int swz = ((lane & 7) ^ lr) * 8;
    #pragma unroll
    for (int ii = 0; ii < 4; ++ii) {
        const int rowbase = w * 32 + ii * 8;
        const ushort* src = g + (size_t)(rowbase + lr) * NC + swz;
        __builtin_amdgcn_global_load_lds((const __attribute__((address_space(1))) void*)src,
                                         (__attribute__((address_space(3))) void*)(lds + rowbase * 64),
                                         16, 0, 0);
    }
}

template<int EPI>
__global__ __launch_bounds__(256)
void gemm_mfma(const ushort* __restrict__ A, const ushort* __restrict__ Bt,
               void* __restrict__ Cout, const float* __restrict__ bias,
               const ushort* __restrict__ resb, int Mtot)
{
    __shared__ __align__(16) ushort smem[128 * 136];
    ushort* As = smem;
    ushort* Bs = smem + 128 * 64;

    const int t = threadIdx.x;
    const int lane = t & 63, w = t >> 6;
    const int wm = w >> 1, wn = w & 1;

    const int l = blockIdx.x;
    const int chunk = (EPI == 0) ? 108 : 36;          // grid/8
    const int mt    = (EPI == 0) ? 6 : 2;
    const int id2 = (l & 7) * chunk + (l >> 3);
    const int n_tile = id2 / mt;
    const int n0 = n_tile * 128;
    const int m0 = (id2 - n_tile * mt) * 128;

    const ushort* Ag = A + (size_t)m0 * NC;
    const ushort* Bg = Bt + (size_t)n0 * NC;

    f32x4 acc[4][4];
    #pragma unroll
    for (int i = 0; i < 4; ++i)
        #pragma unroll
        for (int j = 0; j < 4; ++j)
            acc[i][j] = (f32x4){0.f, 0.f, 0.f, 0.f};

    for (int k0 = 0; k0 < NC; k0 += 64) {
        stage_tile(Ag + k0, As, w, lane);
        stage_tile(Bg + k0, Bs, w, lane);
        __syncthreads();
        #pragma unroll
        for (int ks = 0; ks < 2; ++ks) {
            const int kc = (lane >> 4) + ks * 4;
            const int sw = (kc ^ (lane & 7)) * 8;
            short8v af[4], bf_[4];
            #pragma unroll
            for (int f = 0; f < 4; ++f) {
                af[f]  = *(const short8v*)(As + (wm * 64 + f * 16 + (lane & 15)) * 64 + sw);
                bf_[f] = *(const short8v*)(Bs + (wn * 64 + f * 16 + (lane & 15)) * 64 + sw);
            }
            #pragma unroll
            for (int fi = 0; fi < 4; ++fi)
                #pragma unroll
                for (int fj = 0; fj < 4; ++fj)
                    acc[fi][fj] = __builtin_amdgcn_mfma_f32_16x16x32_bf16(af[fi], bf_[fj], acc[fi][fj], 0, 0, 0);
        }
        __syncthreads();
    }

    const int b = n0 / HW;
    const int hw0 = n0 - b * HW;

    if constexpr (EPI == 0) {
        #pragma unroll
        for (int fi = 0; fi < 4; ++fi)
            #pragma unroll
            for (int fj = 0; fj < 4; ++fj) {
                const int hwl = wn * 64 + fj * 16 + (lane & 15);
                const int ml  = wm * 64 + fi * 16 + (lane >> 4) * 4;
                ushort4 v4;
                v4.x = f2bf(acc[fi][fj][0]);
                v4.y = f2bf(acc[fi][fj][1]);
                v4.z = f2bf(acc[fi][fj][2]);
                v4.w = f2bf(acc[fi][fj][3]);
                *(ushort4*)(smem + hwl * 136 + ml) = v4;
            }
        __syncthreads();
        ushort* C = (ushort*)Cout;
        #pragma unroll
        for (int it = 0; it < 8; ++it) {
            const int cid = it * 256 + t;
            const int hwl = cid >> 4, mc = (cid & 15) * 8;
            const uint4 v = *(const uint4*)(smem + hwl * 136 + mc);
            *(uint4*)(C + ((size_t)b * HW + hw0 + hwl) * (size_t)Mtot + m0 + mc) = v;
        }
    } else {
        float* C = (float*)Cout;
        const int ncol = hw0 + wn * 64 + (lane & 15);
        #pragma unroll
        for (int fi = 0; fi < 4; ++fi)
            #pragma unroll
            for (int r = 0; r < 4; ++r) {
                const int m = m0 + wm * 64 + fi * 16 + (lane >> 4) * 4 + r;
                const float bm = bias[m];
                const size_t base = ((size_t)b * NC + m) * HW + ncol;
                #pragma unroll
                for (int fj = 0; fj < 4; ++fj)
                    C[base + fj * 16] = acc[fi][fj][r] + bm + bf2f(resb[base + fj * 16]);
            }
    }
}

// ---------------------------------------------------------------------------
// Attention via MFMA, transposed q/k LDS. qkvp bf16 pixel-major [b][hw][768],
// q pre-scaled by SCALE*log2e (softmax in exp2 domain, no max-subtract).
// Block = 16-px strip, 4 waves, 4 px/wave, one 32x32x16 MFMA per pixel.
// khT/qhT: [ch][row] stride 74 (word-stride 37, conflict-free); rows 54..73
// zeroed so hi-lane unused k-slot pairs read 0. Fragments = 4 ds_read_b32
// each (aligned row pairs); spurious rows masked on q side only (0*k = 0).
// ---------------------------------------------------------------------------
__global__ __launch_bounds__(256)
void attn_mfma(const ushort* __restrict__ qkvp, ushort* __restrict__ att)
{
    __shared__ ushort khT[32 * 74];  // [ch][row]
    __shared__ ushort qhT[32 * 74];
    __shared__ ushort vh[54 * 40];   // [halo px][32 ch]
    __shared__ float  vs[16 * 32];   // [center px][32 m]

    const int t = threadIdx.x;
    const int sraw = blockIdx.x;                       // 0..575
    const int strip = (sraw & 7) * 72 + (sraw >> 3);   // XCD-chunked
    const int h = blockIdx.y;
    const int b = blockIdx.z;
    const int i0 = strip / 6;
    const int j0 = (strip - (strip / 6) * 6) * 16;

    const ushort* P = qkvp + (size_t)b * HW * 768;
    const int qo = h * HD, ko = NC + h * HD, vo = 2 * NC + h * HD;

    // zero rows 54..73 of khT/qhT: 2 arr x 32 ch x 10 row-pairs = 640 b32
    for (int z = t; z < 640; z += 256) {
        const int arr = z & 1, rest = z >> 1;
        const int ch = rest & 31, rp = rest >> 5;      // rp 0..9
        ushort* dst = (arr ? qhT : khT) + ch * 74 + 54 + rp * 2;
        *(unsigned*)dst = 0u;
    }

    // stage halos: 54 px x 4 chunks of 8 ch; q/k scattered transposed
    if (t < 216) {
        const int px = t >> 2, c8 = (t & 3) * 8;
        const int dy = px / 18, dx = px - dy * 18;
        const int gi = i0 - 1 + dy, gj = j0 - 1 + dx;
        uint4 qv = {0, 0, 0, 0}, kv = {0, 0, 0, 0}, vv = {0, 0, 0, 0};
        if (gi >= 0 && gi < H96 && gj >= 0 && gj < W96) {
            const ushort* pp = P + ((size_t)gi * W96 + gj) * 768;
            qv = *(const uint4*)(pp + qo + c8);
            kv = *(const uint4*)(pp + ko + c8);
            vv = *(const uint4*)(pp + vo + c8);
        }
        *(uint4*)(vh + px * 40 + c8) = vv;
        const unsigned ku[4] = {kv.x, kv.y, kv.z, kv.w};
        const unsigned qu[4] = {qv.x, qv.y, qv.z, qv.w};
        #pragma unroll
        for (int i = 0; i < 4; ++i) {
            khT[(c8 + 2 * i)     * 74 + px] = (ushort)(ku[i] & 0xFFFFu);
            khT[(c8 + 2 * i + 1) * 74 + px] = (ushort)(ku[i] >> 16);
            qhT[(c8 + 2 * i)     * 74 + px] = (ushort)(qu[i] & 0xFFFFu);
            qhT[(c8 + 2 * i + 1) * 74 + px] = (ushort)(qu[i] >> 16);
        }
    }
    __syncthreads();

    // vsum (3x3 box sum of v) in f32
    {
        const int px = t >> 4, m2 = (t & 15) * 2;
        float a0 = 0.f, a1 = 0.f;
        #pragma unroll
        for (int dy = 0; dy < 3; ++dy)
            #pragma unroll
            for (int dx = 0; dx < 3; ++dx) {
                const ushort* pv = vh + (dy * 18 + px + dx) * 40 + m2;
                a0 += bf2f(pv[0]);
                a1 += bf2f(pv[1]);
            }
        vs[px * 32 + m2]     = a0;
        vs[px * 32 + m2 + 1] = a1;
    }
    __syncthreads();

    const int lane = t & 63, w = t >> 6;
    const int hi = lane >> 5, ch = lane & 31;
    const ushort* kb = khT + ch * 74 + hi * 36;
    const ushort* qb = qhT + ch * 74 + hi * 36;

    #pragma unroll
    for (int p = 0; p < 4; ++p) {
        const int c = w * 4 + p;

        unsigned kk0, kk1, kk2, kk3, qq0, qq1, qq2, qq3;
        if ((p & 1) == 0) {
            kk0 = *(const unsigned*)(kb + c);      kk1 = *(const unsigned*)(kb + c + 2);
            kk2 = *(const unsigned*)(kb + c + 18); kk3 = *(const unsigned*)(kb + c + 20);
            qq0 = *(const unsigned*)(qb + c);
            qq1 = *(const unsigned*)(qb + c + 2)  & 0x0000FFFFu;   // spurious row c+3
            qq2 = *(const unsigned*)(qb + c + 18);
            qq3 = *(const unsigned*)(qb + c + 20) & 0x0000FFFFu;   // spurious row c+21
        } else {
            kk0 = *(const unsigned*)(kb + c - 1);  kk1 = *(const unsigned*)(kb + c + 1);
            kk2 = *(const unsigned*)(kb + c + 17); kk3 = *(const unsigned*)(kb + c + 19);
            qq0 = *(const unsigned*)(qb + c - 1)  & 0xFFFF0000u;   // spurious row c-1
            qq1 = *(const unsigned*)(qb + c + 1);
            qq2 = *(const unsigned*)(qb + c + 17) & 0xFFFF0000u;   // spurious row c+17
            qq3 = *(const unsigned*)(qb + c + 19);
        }

        union { unsigned u[4]; short8v v; } A_, B_;
        A_.u[0] = kk0; A_.u[1] = kk1; A_.u[2] = kk2; A_.u[3] = kk3;
        B_.u[0] = qq0; B_.u[1] = qq1; B_.u[2] = qq2; B_.u[3] = qq3;

        f32x16 dm;
        #pragma unroll
        for (int r = 0; r < 16; ++r) dm[r] = 0.f;
        dm = __builtin_amdgcn_mfma_f32_32x32x16_bf16(A_.v, B_.v, dm, 0, 0, 0);

        float vsv[16];
        #pragma unroll
        for (int g = 0; g < 4; ++g) {
            const float4 vv = *(const float4*)(vs + c * 32 + g * 8 + hi * 4);
            vsv[g * 4 + 0] = vv.x; vsv[g * 4 + 1] = vv.y;
            vsv[g * 4 + 2] = vv.z; vsv[g * 4 + 3] = vv.w;
        }

        // softmax over m in exp2 domain (dots pre-scaled by SCALE*log2e)
        float sum = 0.f, out = 0.f;
        #pragma unroll
        for (int r = 0; r < 16; ++r) {
            const float pe = __builtin_amdgcn_exp2f(dm[r]);
            sum += pe;
            out = fmaf(pe, vsv[r], out);
        }
        sum += __shfl_xor(sum, 32);
        out += __shfl_xor(out, 32);

        if (hi == 0) {
            const float inv = __builtin_amdgcn_rcpf(sum);
            att[((size_t)b * HW + (size_t)i0 * W96 + j0 + c) * NC + h * HD + ch] =
                f2bf(out * inv);
        }
    }
}

// ---------------------------------------------------------------------------
extern "C" void kernel_launch(void* const* d_in, const int* in_sizes, int n_in,
                              void* d_out, int out_size, void* d_ws, size_t ws_size,
                              hipStream_t stream)
{
    (void)in_sizes; (void)n_in; (void)out_size; (void)ws_size;
    const float* x     = (const float*)d_in[0];
    const float* w_qkv = (const float*)d_in[1];
    const float* w_out = (const float*)d_in[2];
    const float* b_out = (const float*)d_in[3];
    float* out = (float*)d_out;

    ushort* qkvp = (ushort*)d_ws;                        // [B*HW][768] bf16 28.3 MB
    ushort* attb = qkvp + (size_t)NB * HW * 768;         // [B*HW][256] bf16  9.4 MB
    ushort* xt   = attb + (size_t)NB * HW * NC;          // [B*HW][256] bf16  9.4 MB
    ushort* wqb  = xt   + (size_t)NB * HW * NC;          // [768][256] bf16
    ushort* wob  = wqb  + 768 * NC;                      // [256][256] bf16
    ushort* xbm  = wob  + NC * NC;                       // [B][256][HW] bf16 9.4 MB

    x_to_bf16t<<<dim3(HW / 32, NC / 32, NB), 256, 0, stream>>>(x, xt, xbm);
    conv_w<<<dim3(256), 256, 0, stream>>>(w_qkv, w_out, wqb, wob);
    gemm_mfma<0><<<dim3(864), 256, 0, stream>>>(wqb, xt, qkvp, nullptr, nullptr, 768);
    attn_mfma<<<dim3(576, NHEADS, NB), 256, 0, stream>>>(qkvp, attb);
    gemm_mfma<1><<<dim3(288), 256, 0, stream>>>(wob, attb, out, b_out, xbm, 256);
}